// Round 14
// baseline (319.660 us; speedup 1.0000x reference)
//
#include <hip/hip_runtime.h>
#include <hip/hip_bf16.h>
#include <math.h>

#define NN 1536
#define TT 10
#define DD 64
#define NHEAD 4
#define HDIM 16
#define PP 1178880   // NN*(NN-1)/2 = 4605 * 256 exactly; = 18420 * 64

// ws layout (float offsets) — r11-proven:
#define WS_W2F   0        // 16384 ushort = 8192 float slots
#define WS_TXYT  8192     // 20*1536 = 30720 -> 38912
#define WS_GI    38912    // 1536*128 = 196608 -> 235520
#define WS_GJT4  235520   // 196608 -> 432128
#define WS_NODEA 432128   // 98304 -> 530432
#define WS_NODEB 530432   // 98304 -> 628736

using bf16x8 = __attribute__((ext_vector_type(8))) short;
using f32x4  = __attribute__((ext_vector_type(4))) float;

static __device__ __forceinline__ float fsqrt(float x) { return __builtin_amdgcn_sqrtf(x); }
static __device__ __forceinline__ float frcp(float x)  { return __builtin_amdgcn_rcpf(x); }
static __device__ __forceinline__ float fexp(float x)  {
    return __builtin_amdgcn_exp2f(x * 1.44269504088896f);
}
static __device__ __forceinline__ float fsigmoid_neg(float e_arg) {
    return frcp(1.f + fexp(e_arg));     // 1/(1+exp(e_arg))
}

static __device__ __forceinline__ unsigned short f2bf_rn(float f) {
    unsigned int u = __float_as_uint(f);
    unsigned int r = (u + 0x7FFFu + ((u >> 16) & 1u)) >> 16;
    return (unsigned short)r;
}
static __device__ __forceinline__ float bf2f(unsigned short h) {
    return __uint_as_float(((unsigned int)h) << 16);
}

static __device__ __forceinline__ float dot64(const float* __restrict__ a,
                                              const float* __restrict__ b) {
    float s = 0.f;
#pragma unroll
    for (int c = 0; c < 64; c += 4) {
        float4 av = *reinterpret_cast<const float4*>(a + c);
        float4 bv = *reinterpret_cast<const float4*>(b + c);
        s = fmaf(av.x, bv.x, s);
        s = fmaf(av.y, bv.y, s);
        s = fmaf(av.z, bv.z, s);
        s = fmaf(av.w, bv.w, s);
    }
    return s;
}

static __device__ __forceinline__ void invert_p(int p, int& io, int& jo) {
    const float Df = (float)((2 * NN - 1) * (2 * NN - 1) - 8 * p);
    int i = (int)(((float)(2 * NN - 1) - fsqrt(Df)) * 0.5f);
    i = i < 0 ? 0 : (i > NN - 2 ? NN - 2 : i);
    while (i * (2 * NN - 1 - i) / 2 > p) --i;
    while ((i + 1) * (2 * NN - 2 - i) / 2 <= p) ++i;
    io = i;
    jo = i + 1 + (p - i * (2 * NN - 1 - i) / 2);
}

// accumulate 16-wide chunk: acc += x[0..15] . w(4 float4 regs)
#define FMA16(acc, xr, w0, w1, w2, w3)                                   \
    {                                                                    \
        float4 x0 = *reinterpret_cast<const float4*>(xr);                \
        float4 x1 = *reinterpret_cast<const float4*>(xr + 4);            \
        float4 x2 = *reinterpret_cast<const float4*>(xr + 8);            \
        float4 x3 = *reinterpret_cast<const float4*>(xr + 12);           \
        acc = fmaf(x0.x, w0.x, acc); acc = fmaf(x0.y, w0.y, acc);        \
        acc = fmaf(x0.z, w0.z, acc); acc = fmaf(x0.w, w0.w, acc);        \
        acc = fmaf(x1.x, w1.x, acc); acc = fmaf(x1.y, w1.y, acc);        \
        acc = fmaf(x1.z, w1.z, acc); acc = fmaf(x1.w, w1.w, acc);        \
        acc = fmaf(x2.x, w2.x, acc); acc = fmaf(x2.y, w2.y, acc);        \
        acc = fmaf(x2.z, w2.z, acc); acc = fmaf(x2.w, w2.w, acc);        \
        acc = fmaf(x3.x, w3.x, acc); acc = fmaf(x3.y, w3.y, acc);        \
        acc = fmaf(x3.z, w3.z, acc); acc = fmaf(x3.w, w3.w, acc);        \
    }

// ---------------- Transformer encoder layer (+aux: w2f, txyT), 128 thr/block ----------------
__global__ __launch_bounds__(128) void k_transformer(
    const float* __restrict__ traj,
    const float* __restrict__ wqkv, const float* __restrict__ bqkv,
    const float* __restrict__ wo,   const float* __restrict__ bo,
    const float* __restrict__ g1,   const float* __restrict__ b1,
    const float* __restrict__ fw1,  const float* __restrict__ fb1,
    const float* __restrict__ fw2,  const float* __restrict__ fb2,
    const float* __restrict__ g2,   const float* __restrict__ b2,
    const float* __restrict__ e_w2,
    float* __restrict__ node_out, unsigned short* __restrict__ w2f,
    float* __restrict__ txyT)
{
    const int bid = blockIdx.x, tid = threadIdx.x;

    if (bid >= NN) {
        const int s = bid - NN;
        if (s < 64) {
#pragma unroll
            for (int q = 0; q < 2; ++q) {
                const int idx = s * 256 + q * 128 + tid;
                int e = idx & 7, lane = (idx >> 3) & 63;
                int half = (idx >> 9) & 1, kk = (idx >> 10) & 3, nt = (idx >> 12) & 3;
                int n = nt * 16 + (lane & 15);
                int k = kk * 32 + (lane >> 4) * 8 + e;
                float v = e_w2[n * 128 + k];
                unsigned short hi = f2bf_rn(v);
                unsigned short lo = f2bf_rn(v - bf2f(hi));
                w2f[idx] = half ? lo : hi;
            }
        } else {
            const int tc = s - 64;       // 0..19
            const int t = tc >> 1, c = tc & 1;
            for (int j = tid; j < NN; j += 128)
                txyT[(size_t)tc * NN + j] = traj[((size_t)j * TT + t) * DD + c];
        }
        return;
    }

    __shared__ __align__(16) float xs[TT][DD];
    __shared__ __align__(16) float qkvs[TT][3 * DD];
    __shared__ __align__(16) float cs[TT][DD];
    __shared__ __align__(16) float ys[TT][DD];
    __shared__ float mv[TT][2];

    const float* xg = traj + (size_t)bid * TT * DD;
    for (int idx = tid; idx < TT * DD; idx += 128)
        xs[idx / DD][idx % DD] = xg[idx];
    __syncthreads();

    // ---- QKV ----
    {
        float acc[TT];
        const float bq = bqkv[tid];
#pragma unroll
        for (int t = 0; t < TT; ++t) acc[t] = bq;
        const float* wrow = wqkv + (size_t)tid * DD;
#pragma unroll
        for (int c = 0; c < 4; ++c) {
            float4 w0 = *reinterpret_cast<const float4*>(wrow + 16 * c);
            float4 w1 = *reinterpret_cast<const float4*>(wrow + 16 * c + 4);
            float4 w2 = *reinterpret_cast<const float4*>(wrow + 16 * c + 8);
            float4 w3 = *reinterpret_cast<const float4*>(wrow + 16 * c + 12);
#pragma unroll
            for (int t = 0; t < TT; ++t)
                FMA16(acc[t], &xs[t][16 * c], w0, w1, w2, w3);
        }
#pragma unroll
        for (int t = 0; t < TT; ++t) qkvs[t][tid] = acc[t];

        const int o2 = 128 + (tid >> 1);
        const int t0 = (tid & 1) * 5;
        float acc2[5];
        const float bq2 = bqkv[o2];
#pragma unroll
        for (int tt = 0; tt < 5; ++tt) acc2[tt] = bq2;
        const float* wrow2 = wqkv + (size_t)o2 * DD;
#pragma unroll
        for (int c = 0; c < 4; ++c) {
            float4 w0 = *reinterpret_cast<const float4*>(wrow2 + 16 * c);
            float4 w1 = *reinterpret_cast<const float4*>(wrow2 + 16 * c + 4);
            float4 w2 = *reinterpret_cast<const float4*>(wrow2 + 16 * c + 8);
            float4 w3 = *reinterpret_cast<const float4*>(wrow2 + 16 * c + 12);
#pragma unroll
            for (int tt = 0; tt < 5; ++tt)
                FMA16(acc2[tt], &xs[t0 + tt][16 * c], w0, w1, w2, w3);
        }
#pragma unroll
        for (int tt = 0; tt < 5; ++tt) qkvs[t0 + tt][o2] = acc2[tt];
    }
    __syncthreads();

    // ---- attention ----
    if (tid < NHEAD * TT) {
        int h = tid / TT, t = tid % TT;
        float sc[TT];
        float mx = -1e30f;
#pragma unroll
        for (int s = 0; s < TT; ++s) {
            float a = 0.f;
#pragma unroll
            for (int d = 0; d < HDIM; ++d)
                a = fmaf(qkvs[t][h * HDIM + d], qkvs[s][DD + h * HDIM + d], a);
            a *= 0.25f;
            sc[s] = a;
            mx = fmaxf(mx, a);
        }
        float den = 0.f;
#pragma unroll
        for (int s = 0; s < TT; ++s) { sc[s] = fexp(sc[s] - mx); den += sc[s]; }
        float inv = frcp(den);
#pragma unroll
        for (int d = 0; d < HDIM; ++d) {
            float a = 0.f;
#pragma unroll
            for (int s = 0; s < TT; ++s)
                a = fmaf(sc[s], qkvs[s][2 * DD + h * HDIM + d], a);
            cs[t][h * HDIM + d] = a * inv;
        }
    }
    __syncthreads();

    // ---- out-proj + residual ----
    {
        const int o = tid & 63, t0 = (tid >> 6) * 5;
        float acc[5];
        const float bv = bo[o];
#pragma unroll
        for (int tt = 0; tt < 5; ++tt) acc[tt] = bv;
        const float* wrow = wo + (size_t)o * DD;
#pragma unroll
        for (int c = 0; c < 4; ++c) {
            float4 w0 = *reinterpret_cast<const float4*>(wrow + 16 * c);
            float4 w1 = *reinterpret_cast<const float4*>(wrow + 16 * c + 4);
            float4 w2 = *reinterpret_cast<const float4*>(wrow + 16 * c + 8);
            float4 w3 = *reinterpret_cast<const float4*>(wrow + 16 * c + 12);
#pragma unroll
            for (int tt = 0; tt < 5; ++tt)
                FMA16(acc[tt], &cs[t0 + tt][16 * c], w0, w1, w2, w3);
        }
#pragma unroll
        for (int tt = 0; tt < 5; ++tt)
            ys[t0 + tt][o] = xs[t0 + tt][o] + acc[tt];
    }
    __syncthreads();

    // ---- LN1 stats ----
    {
        const int t8 = tid >> 3, s8 = tid & 7;
        if (t8 < TT) {
            const float* yr = &ys[t8][s8 * 8];
            float s1 = 0.f;
#pragma unroll
            for (int c = 0; c < 8; c += 4) {
                float4 v = *reinterpret_cast<const float4*>(yr + c);
                s1 += (v.x + v.y) + (v.z + v.w);
            }
#pragma unroll
            for (int m = 1; m < 8; m <<= 1) s1 += __shfl_xor(s1, m);
            const float mean = s1 * (1.f / DD);
            float s2 = 0.f;
#pragma unroll
            for (int c = 0; c < 8; c += 4) {
                float4 v = *reinterpret_cast<const float4*>(yr + c);
                float d0 = v.x - mean, d1 = v.y - mean, d2 = v.z - mean, d3 = v.w - mean;
                s2 = fmaf(d0, d0, fmaf(d1, d1, fmaf(d2, d2, fmaf(d3, d3, s2))));
            }
#pragma unroll
            for (int m = 1; m < 8; m <<= 1) s2 += __shfl_xor(s2, m);
            if (s8 == 0) {
                mv[t8][0] = mean;
                mv[t8][1] = rsqrtf(s2 * (1.f / DD) + 1e-5f);
            }
        }
    }
    __syncthreads();
    for (int idx = tid; idx < TT * DD; idx += 128) {
        int t = idx / DD, o = idx % DD;
        xs[t][o] = (ys[t][o] - mv[t][0]) * mv[t][1] * g1[o] + b1[o];
    }
    __syncthreads();

    // ---- FF1 ----
    {
        const int pcol = tid & 63, t0 = (tid >> 6) * 5;
        float acc[5];
        const float bv = fb1[pcol];
#pragma unroll
        for (int tt = 0; tt < 5; ++tt) acc[tt] = bv;
        const float* wrow = fw1 + (size_t)pcol * DD;
#pragma unroll
        for (int c = 0; c < 4; ++c) {
            float4 w0 = *reinterpret_cast<const float4*>(wrow + 16 * c);
            float4 w1 = *reinterpret_cast<const float4*>(wrow + 16 * c + 4);
            float4 w2 = *reinterpret_cast<const float4*>(wrow + 16 * c + 8);
            float4 w3 = *reinterpret_cast<const float4*>(wrow + 16 * c + 12);
#pragma unroll
            for (int tt = 0; tt < 5; ++tt)
                FMA16(acc[tt], &xs[t0 + tt][16 * c], w0, w1, w2, w3);
        }
#pragma unroll
        for (int tt = 0; tt < 5; ++tt)
            cs[t0 + tt][pcol] = fmaxf(acc[tt], 0.f);
    }
    __syncthreads();

    // ---- FF2 + residual ----
    {
        const int o = tid & 63, t0 = (tid >> 6) * 5;
        float acc[5];
        const float bv = fb2[o];
#pragma unroll
        for (int tt = 0; tt < 5; ++tt) acc[tt] = bv;
        const float* wrow = fw2 + (size_t)o * DD;
#pragma unroll
        for (int c = 0; c < 4; ++c) {
            float4 w0 = *reinterpret_cast<const float4*>(wrow + 16 * c);
            float4 w1 = *reinterpret_cast<const float4*>(wrow + 16 * c + 4);
            float4 w2 = *reinterpret_cast<const float4*>(wrow + 16 * c + 8);
            float4 w3 = *reinterpret_cast<const float4*>(wrow + 16 * c + 12);
#pragma unroll
            for (int tt = 0; tt < 5; ++tt)
                FMA16(acc[tt], &cs[t0 + tt][16 * c], w0, w1, w2, w3);
        }
#pragma unroll
        for (int tt = 0; tt < 5; ++tt)
            ys[t0 + tt][o] = xs[t0 + tt][o] + acc[tt];
    }
    __syncthreads();

    // ---- LN2 stats ----
    {
        const int t8 = tid >> 3, s8 = tid & 7;
        if (t8 < TT) {
            const float* yr = &ys[t8][s8 * 8];
            float s1 = 0.f;
#pragma unroll
            for (int c = 0; c < 8; c += 4) {
                float4 v = *reinterpret_cast<const float4*>(yr + c);
                s1 += (v.x + v.y) + (v.z + v.w);
            }
#pragma unroll
            for (int m = 1; m < 8; m <<= 1) s1 += __shfl_xor(s1, m);
            const float mean = s1 * (1.f / DD);
            float s2 = 0.f;
#pragma unroll
            for (int c = 0; c < 8; c += 4) {
                float4 v = *reinterpret_cast<const float4*>(yr + c);
                float d0 = v.x - mean, d1 = v.y - mean, d2 = v.z - mean, d3 = v.w - mean;
                s2 = fmaf(d0, d0, fmaf(d1, d1, fmaf(d2, d2, fmaf(d3, d3, s2))));
            }
#pragma unroll
            for (int m = 1; m < 8; m <<= 1) s2 += __shfl_xor(s2, m);
            if (s8 == 0) {
                mv[t8][0] = mean;
                mv[t8][1] = rsqrtf(s2 * (1.f / DD) + 1e-5f);
            }
        }
    }
    __syncthreads();

    if (tid < DD) {
        float acc = 0.f;
#pragma unroll
        for (int t = 0; t < TT; ++t)
            acc += (ys[t][tid] - mv[t][0]) * mv[t][1];
        node_out[bid * DD + tid] = acc * g2[tid] * (1.f / TT) + b2[tid];
    }
}

// ---------------- GCN fused layer: Y = relu((A@X)@W^T + b); 512 thr, 4 rows/blk ----------------
__global__ __launch_bounds__(512) void k_gcn(
    const float* __restrict__ A, const float* __restrict__ X,
    const float* __restrict__ W, const float* __restrict__ b,
    float* __restrict__ Y)
{
    __shared__ __align__(16) float part[8][68];
    const int tid = threadIdx.x;
    const int lane = tid & 63;
    const int wv = tid >> 6;               // 0..7: row r = wv>>1, j-half = wv&1
    const int r = wv >> 1, jh = wv & 1;
    const int i = __builtin_amdgcn_readfirstlane(blockIdx.x * 4 + r);

    const float* arow = A + (size_t)i * NN + jh * (NN / 2);
    const float* xp = X + (size_t)jh * (NN / 2) * 64 + lane;
    float acc = 0.f;
#pragma unroll 8
    for (int jj = 0; jj < NN / 2; ++jj)
        acc = fmaf(arow[jj], xp[(size_t)jj * 64], acc);
    part[wv][lane] = acc;
    __syncthreads();

    if (tid < 256) {
        const int o = tid & 63, r2 = tid >> 6;
        float z = b[o] + dot64(&part[2 * r2][0], W + o * 64)
                       + dot64(&part[2 * r2 + 1][0], W + o * 64);
        Y[(size_t)(blockIdx.x * 4 + r2) * 64 + o] = fmaxf(z, 0.f);
    }
}

// ---------------- GCN layer 3 + fused edge-prep (gi, gjT4) ----------------
__global__ __launch_bounds__(512) void k_gcn3(
    const float* __restrict__ A, const float* __restrict__ X,
    const float* __restrict__ W, const float* __restrict__ b,
    const float* __restrict__ e_w1, const float* __restrict__ e_b1,
    float* __restrict__ gi_t, float* __restrict__ gjT4)
{
    __shared__ __align__(16) float part[8][68];
    __shared__ __align__(16) float nrow[4][68];
    const int tid = threadIdx.x;
    const int lane = tid & 63;
    const int wv = tid >> 6;
    const int r = wv >> 1, jh = wv & 1;
    const int i = __builtin_amdgcn_readfirstlane(blockIdx.x * 4 + r);

    const float* arow = A + (size_t)i * NN + jh * (NN / 2);
    const float* xp = X + (size_t)jh * (NN / 2) * 64 + lane;
    float acc = 0.f;
#pragma unroll 8
    for (int jj = 0; jj < NN / 2; ++jj)
        acc = fmaf(arow[jj], xp[(size_t)jj * 64], acc);
    part[wv][lane] = acc;
    __syncthreads();

    if (tid < 256) {
        const int o = tid & 63, r2 = tid >> 6;
        float z = b[o] + dot64(&part[2 * r2][0], W + o * 64)
                       + dot64(&part[2 * r2 + 1][0], W + o * 64);
        nrow[r2][o] = fmaxf(z, 0.f);
    }
    __syncthreads();

    // gi + gjT4: 512 threads = 4 rows x 128 o, one of each per thread
    const int rr = tid >> 7;        // 0..3
    const int oo = tid & 127;
    const int i2 = blockIdx.x * 4 + rr;
    gi_t[(size_t)i2 * 128 + oo] = e_b1[oo] + dot64(&nrow[rr][0], e_w1 + oo * 138);
    gjT4[((size_t)(oo >> 2) * NN + i2) * 4 + (oo & 3)] =
        dot64(&nrow[rr][0], e_w1 + oo * 138 + 64);
}

// ---------------- edge predictor: MFMA, 64 pairs/block, 4 waves, half-K tiles ----------------
// LDS 20224 B -> 8 blocks/CU; (pi,pj) computed once by wave0, broadcast via hs[.][10]
__global__ __launch_bounds__(256, 8) void k_edge(
    const float* __restrict__ txyT,
    const float* __restrict__ gi_t,      // stride 128 per i
    const float* __restrict__ gjT4,
    const float* __restrict__ e_w1,
    const unsigned short* __restrict__ w2f,
    const float* __restrict__ e_b2,
    const float* __restrict__ e_w3, const float* __restrict__ e_b3,
    float* __restrict__ out)
{
    __shared__ __align__(16) unsigned short Ah[64 * 64];   // 8192 B
    __shared__ __align__(16) unsigned short Al[64 * 64];   // 8192 B
    __shared__ __align__(16) float hs[64][11];             // 2816 B (slot 10 = packed pi/pj)
    __shared__ __align__(16) float zsh[4][64];             // 1024 B

    const int tid  = threadIdx.x;
    const int lane = tid & 63;
    const int wv   = __builtin_amdgcn_readfirstlane(tid >> 6);  // wave 0..3
    const int p    = blockIdx.x * 64 + lane;

    // ---- wave 0: invert p, hist + dmin -> LDS (stores deferred) ----
    float dmin = 3.4e38f;
    if (wv == 0) {
        int pi0, pj0;
        invert_p(p, pi0, pj0);
#pragma unroll
        for (int t = 0; t < 10; ++t) {
            float dx = txyT[(size_t)(2 * t) * NN + pi0] - txyT[(size_t)(2 * t) * NN + pj0];
            float dy = txyT[(size_t)(2 * t + 1) * NN + pi0] - txyT[(size_t)(2 * t + 1) * NN + pj0];
            float d = fsqrt(fmaf(dx, dx, dy * dy));
            dmin = fminf(dmin, d);
            hs[lane][t] = fsigmoid_neg(50.f - 10.f * d);   // sigmoid(10d-50)
        }
        hs[lane][10] = __uint_as_float(((unsigned int)pi0 << 16) | (unsigned int)pj0);
    }
    __syncthreads();

    float hist[10];
#pragma unroll
    for (int t = 0; t < 10; ++t) hist[t] = hs[lane][t];
    const unsigned int pij = __float_as_uint(hs[lane][10]);
    const int pi = (int)(pij >> 16);
    const int pj = (int)(pij & 0xFFFFu);

    f32x4 acc[4];
#pragma unroll
    for (int pt = 0; pt < 4; ++pt) acc[pt] = (f32x4){0.f, 0.f, 0.f, 0.f};

#pragma unroll
    for (int h = 0; h < 2; ++h) {
        // ---- phase 1: 16 o's for o-window [h*64 + wv*16, +16) ----
        const int ob = h * 64 + wv * 16;
        const float* giRow = gi_t + (size_t)pi * 128 + ob;
        unsigned int ahp[8], alp[8];
#pragma unroll
        for (int q2 = 0; q2 < 4; ++q2) {
            const int o = ob + 4 * q2;
            const float4 gi4 = *reinterpret_cast<const float4*>(giRow + 4 * q2);
            const float4 gj4 = *reinterpret_cast<const float4*>(
                gjT4 + ((size_t)(o >> 2) * NN + pj) * 4);
            float av[4];
#pragma unroll
            for (int k = 0; k < 4; ++k) {
                float a = (&gi4.x)[k] + (&gj4.x)[k];
                const float* wh = e_w1 + (o + k) * 138 + 128;   // uniform -> scalar
#pragma unroll
                for (int t = 0; t < 10; ++t) a = fmaf(hist[t], wh[t], a);
                av[k] = fmaxf(a, 0.f);
            }
            const unsigned int u0 = __float_as_uint(av[0]), u1 = __float_as_uint(av[1]);
            const unsigned int u2 = __float_as_uint(av[2]), u3 = __float_as_uint(av[3]);
            ahp[2 * q2]     = __builtin_amdgcn_perm(u1, u0, 0x07060302);
            ahp[2 * q2 + 1] = __builtin_amdgcn_perm(u3, u2, 0x07060302);
            const float l0 = av[0] - __uint_as_float(u0 & 0xFFFF0000u);
            const float l1 = av[1] - __uint_as_float(u1 & 0xFFFF0000u);
            const float l2 = av[2] - __uint_as_float(u2 & 0xFFFF0000u);
            const float l3 = av[3] - __uint_as_float(u3 & 0xFFFF0000u);
            alp[2 * q2]     = __builtin_amdgcn_perm(__float_as_uint(l1), __float_as_uint(l0), 0x07060302);
            alp[2 * q2 + 1] = __builtin_amdgcn_perm(__float_as_uint(l3), __float_as_uint(l2), 0x07060302);
        }

        if (h == 1) __syncthreads();    // all waves done reading half-0 tiles

        // write tiles: row = lane (128 B rows), XOR row swizzle
        char* ahb = (char*)Ah + lane * 128;
        char* alb = (char*)Al + lane * 128;
#pragma unroll
        for (int c = 0; c < 2; ++c) {
            const int boff = ((wv << 5) + (c << 4)) ^ ((lane & 7) << 4);
            *reinterpret_cast<uint4*>(ahb + boff) = *reinterpret_cast<uint4*>(&ahp[4 * c]);
            *reinterpret_cast<uint4*>(alb + boff) = *reinterpret_cast<uint4*>(&alp[4 * c]);
        }

        // B-frags for this half: global kk = 2h + kkl
        bf16x8 bh[2], bl[2];
#pragma unroll
        for (int kkl = 0; kkl < 2; ++kkl) {
            const unsigned short* bb =
                w2f + ((size_t)(wv * 4 + 2 * h + kkl) * 2) * 512 + lane * 8;
            bh[kkl] = *reinterpret_cast<const bf16x8*>(bb);
            bl[kkl] = *reinterpret_cast<const bf16x8*>(bb + 512);
        }
        __syncthreads();

        // ---- MFMA: 2 kkl x 4 pt x 3 terms ----
        const char* ahr = (const char*)Ah;
        const char* alr = (const char*)Al;
#pragma unroll
        for (int kkl = 0; kkl < 2; ++kkl) {
#pragma unroll
            for (int pt = 0; pt < 4; ++pt) {
                const int row = pt * 16 + (lane & 15);
                const int boff = ((kkl << 6) + ((lane >> 4) << 4)) ^ ((row & 7) << 4);
                bf16x8 afh = *reinterpret_cast<const bf16x8*>(ahr + row * 128 + boff);
                bf16x8 afl = *reinterpret_cast<const bf16x8*>(alr + row * 128 + boff);
                acc[pt] = __builtin_amdgcn_mfma_f32_16x16x32_bf16(afh, bh[kkl], acc[pt], 0, 0, 0);
                acc[pt] = __builtin_amdgcn_mfma_f32_16x16x32_bf16(afh, bl[kkl], acc[pt], 0, 0, 0);
                acc[pt] = __builtin_amdgcn_mfma_f32_16x16x32_bf16(afl, bh[kkl], acc[pt], 0, 0, 0);
            }
        }
    }

    // ---- epilogue ----
    {
        const int m = wv * 16 + (lane & 15);
        const float w3v = e_w3[m];
        const float b2v = e_b2[m];
#pragma unroll
        for (int pt = 0; pt < 4; ++pt) {
            float zs0 = fmaxf(acc[pt][0] + b2v, 0.f) * w3v;
            float zs1 = fmaxf(acc[pt][1] + b2v, 0.f) * w3v;
            float zs2 = fmaxf(acc[pt][2] + b2v, 0.f) * w3v;
            float zs3 = fmaxf(acc[pt][3] + b2v, 0.f) * w3v;
#pragma unroll
            for (int msk = 1; msk < 16; msk <<= 1) {
                zs0 += __shfl_xor(zs0, msk);
                zs1 += __shfl_xor(zs1, msk);
                zs2 += __shfl_xor(zs2, msk);
                zs3 += __shfl_xor(zs3, msk);
            }
            if ((lane & 15) == 0) {
                const int pr = pt * 16 + (lane >> 4) * 4;
                zsh[wv][pr]     = zs0;
                zsh[wv][pr + 1] = zs1;
                zsh[wv][pr + 2] = zs2;
                zsh[wv][pr + 3] = zs3;
            }
        }
    }
    __syncthreads();

    // ---- deferred stores: prob + dmin + hist (hs still live) ----
    if (wv == 0) {
        float z = zsh[0][lane] + zsh[1][lane] + zsh[2][lane] + zsh[3][lane] + e_b3[0];
        out[p] = fsigmoid_neg(-z);
        out[PP + (size_t)p] = dmin;
        float* hp = out + 2 * (size_t)PP + (size_t)p * 10;
#pragma unroll
        for (int t = 0; t < 10; ++t) hp[t] = hs[lane][t];
    }
}

extern "C" void kernel_launch(void* const* d_in, const int* in_sizes, int n_in,
                              void* d_out, int out_size, void* d_ws, size_t ws_size,
                              hipStream_t stream) {
    const float* traj   = (const float*)d_in[0];
    const float* adj    = (const float*)d_in[1];
    const float* w_in   = (const float*)d_in[2];
    const float* b_in   = (const float*)d_in[3];
    const float* w_out  = (const float*)d_in[4];
    const float* b_out  = (const float*)d_in[5];
    const float* ln1g   = (const float*)d_in[6];
    const float* ln1b   = (const float*)d_in[7];
    const float* fw1    = (const float*)d_in[8];
    const float* fb1    = (const float*)d_in[9];
    const float* fw2    = (const float*)d_in[10];
    const float* fb2    = (const float*)d_in[11];
    const float* ln2g   = (const float*)d_in[12];
    const float* ln2b   = (const float*)d_in[13];
    const float* gcn_w  = (const float*)d_in[14];
    const float* gcn_b  = (const float*)d_in[15];
    const float* e_w1   = (const float*)d_in[16];
    const float* e_b1   = (const float*)d_in[17];
    const float* e_w2   = (const float*)d_in[18];
    const float* e_b2   = (const float*)d_in[19];
    const float* e_w3   = (const float*)d_in[20];
    const float* e_b3   = (const float*)d_in[21];

    float* ws    = (float*)d_ws;
    unsigned short* w2f = (unsigned short*)(ws + WS_W2F);
    float* txyT  = ws + WS_TXYT;
    float* gi    = ws + WS_GI;
    float* gjT4  = ws + WS_GJT4;
    float* nodeA = ws + WS_NODEA;
    float* nodeB = ws + WS_NODEB;

    k_transformer<<<NN + 84, 128, 0, stream>>>(traj, w_in, b_in, w_out, b_out,
                                               ln1g, ln1b, fw1, fb1, fw2, fb2,
                                               ln2g, ln2b, e_w2,
                                               nodeA, w2f, txyT);

    k_gcn <<<NN / 4, 512, 0, stream>>>(adj, nodeA, gcn_w,        gcn_b,       nodeB);
    k_gcn <<<NN / 4, 512, 0, stream>>>(adj, nodeB, gcn_w + 4096, gcn_b + 64,  nodeA);
    k_gcn3<<<NN / 4, 512, 0, stream>>>(adj, nodeA, gcn_w + 8192, gcn_b + 128,
                                       e_w1, e_b1, gi, gjT4);

    k_edge<<<PP / 64, 256, 0, stream>>>(txyT, gi, gjT4, e_w1, w2f, e_b2,
                                        e_w3, e_b3, (float*)d_out);
}

// Round 15
// 235.172 us; speedup vs baseline: 1.3593x; 1.3593x over previous
//
#include <hip/hip_runtime.h>
#include <hip/hip_bf16.h>
#include <math.h>

#define NN 1536
#define TT 10
#define DD 64
#define NHEAD 4
#define HDIM 16
#define PP 1178880   // NN*(NN-1)/2 = 4605 * 256 exactly; = 18420 * 64

// ws layout (float offsets)
#define WS_W2F   0        // 16384 ushort = 8192 float slots
#define WS_TXYT  8192     // 20*1536 = 30720 -> 38912
#define WS_GI    38912    // 1536*128 = 196608 -> 235520
#define WS_GJT4  235520   // 196608 -> 432128
#define WS_NODEA 432128   // 98304 -> 530432
#define WS_NODEB 530432   // 98304 -> 628736

using bf16x8 = __attribute__((ext_vector_type(8))) short;
using f32x4  = __attribute__((ext_vector_type(4))) float;

static __device__ __forceinline__ float fsqrt(float x) { return __builtin_amdgcn_sqrtf(x); }
static __device__ __forceinline__ float frcp(float x)  { return __builtin_amdgcn_rcpf(x); }
static __device__ __forceinline__ float fexp(float x)  {
    return __builtin_amdgcn_exp2f(x * 1.44269504088896f);
}
static __device__ __forceinline__ float fsigmoid_neg(float e_arg) {
    return frcp(1.f + fexp(e_arg));     // 1/(1+exp(e_arg))
}

static __device__ __forceinline__ unsigned short f2bf_rn(float f) {
    unsigned int u = __float_as_uint(f);
    unsigned int r = (u + 0x7FFFu + ((u >> 16) & 1u)) >> 16;
    return (unsigned short)r;
}
static __device__ __forceinline__ float bf2f(unsigned short h) {
    return __uint_as_float(((unsigned int)h) << 16);
}

static __device__ __forceinline__ float dot64(const float* __restrict__ a,
                                              const float* __restrict__ b) {
    float s = 0.f;
#pragma unroll
    for (int c = 0; c < 64; c += 4) {
        float4 av = *reinterpret_cast<const float4*>(a + c);
        float4 bv = *reinterpret_cast<const float4*>(b + c);
        s = fmaf(av.x, bv.x, s);
        s = fmaf(av.y, bv.y, s);
        s = fmaf(av.z, bv.z, s);
        s = fmaf(av.w, bv.w, s);
    }
    return s;
}

static __device__ __forceinline__ void invert_p(int p, int& io, int& jo) {
    const float Df = (float)((2 * NN - 1) * (2 * NN - 1) - 8 * p);
    int i = (int)(((float)(2 * NN - 1) - fsqrt(Df)) * 0.5f);
    i = i < 0 ? 0 : (i > NN - 2 ? NN - 2 : i);
    while (i * (2 * NN - 1 - i) / 2 > p) --i;
    while ((i + 1) * (2 * NN - 2 - i) / 2 <= p) ++i;
    io = i;
    jo = i + 1 + (p - i * (2 * NN - 1 - i) / 2);
}

// accumulate 16-wide chunk: acc += x[0..15] . w(4 float4 regs)
#define FMA16(acc, xr, w0, w1, w2, w3)                                   \
    {                                                                    \
        float4 x0 = *reinterpret_cast<const float4*>(xr);                \
        float4 x1 = *reinterpret_cast<const float4*>(xr + 4);            \
        float4 x2 = *reinterpret_cast<const float4*>(xr + 8);            \
        float4 x3 = *reinterpret_cast<const float4*>(xr + 12);           \
        acc = fmaf(x0.x, w0.x, acc); acc = fmaf(x0.y, w0.y, acc);        \
        acc = fmaf(x0.z, w0.z, acc); acc = fmaf(x0.w, w0.w, acc);        \
        acc = fmaf(x1.x, w1.x, acc); acc = fmaf(x1.y, w1.y, acc);        \
        acc = fmaf(x1.z, w1.z, acc); acc = fmaf(x1.w, w1.w, acc);        \
        acc = fmaf(x2.x, w2.x, acc); acc = fmaf(x2.y, w2.y, acc);        \
        acc = fmaf(x2.z, w2.z, acc); acc = fmaf(x2.w, w2.w, acc);        \
        acc = fmaf(x3.x, w3.x, acc); acc = fmaf(x3.y, w3.y, acc);        \
        acc = fmaf(x3.z, w3.z, acc); acc = fmaf(x3.w, w3.w, acc);        \
    }

// ---------------- Transformer encoder layer (+aux: w2f, txyT), 128 thr/block ----------------
__global__ __launch_bounds__(128) void k_transformer(
    const float* __restrict__ traj,
    const float* __restrict__ wqkv, const float* __restrict__ bqkv,
    const float* __restrict__ wo,   const float* __restrict__ bo,
    const float* __restrict__ g1,   const float* __restrict__ b1,
    const float* __restrict__ fw1,  const float* __restrict__ fb1,
    const float* __restrict__ fw2,  const float* __restrict__ fb2,
    const float* __restrict__ g2,   const float* __restrict__ b2,
    const float* __restrict__ e_w2,
    float* __restrict__ node_out, unsigned short* __restrict__ w2f,
    float* __restrict__ txyT)
{
    const int bid = blockIdx.x, tid = threadIdx.x;

    if (bid >= NN) {
        const int s = bid - NN;
        if (s < 64) {
#pragma unroll
            for (int q = 0; q < 2; ++q) {
                const int idx = s * 256 + q * 128 + tid;
                int e = idx & 7, lane = (idx >> 3) & 63;
                int half = (idx >> 9) & 1, kk = (idx >> 10) & 3, nt = (idx >> 12) & 3;
                int n = nt * 16 + (lane & 15);
                int k = kk * 32 + (lane >> 4) * 8 + e;
                float v = e_w2[n * 128 + k];
                unsigned short hi = f2bf_rn(v);
                unsigned short lo = f2bf_rn(v - bf2f(hi));
                w2f[idx] = half ? lo : hi;
            }
        } else {
            const int tc = s - 64;       // 0..19
            const int t = tc >> 1, c = tc & 1;
            for (int j = tid; j < NN; j += 128)
                txyT[(size_t)tc * NN + j] = traj[((size_t)j * TT + t) * DD + c];
        }
        return;
    }

    __shared__ __align__(16) float xs[TT][DD];
    __shared__ __align__(16) float qkvs[TT][3 * DD];
    __shared__ __align__(16) float cs[TT][DD];
    __shared__ __align__(16) float ys[TT][DD];
    __shared__ float mv[TT][2];

    const float* xg = traj + (size_t)bid * TT * DD;
    for (int idx = tid; idx < TT * DD; idx += 128)
        xs[idx / DD][idx % DD] = xg[idx];
    __syncthreads();

    // ---- QKV ----
    {
        float acc[TT];
        const float bq = bqkv[tid];
#pragma unroll
        for (int t = 0; t < TT; ++t) acc[t] = bq;
        const float* wrow = wqkv + (size_t)tid * DD;
#pragma unroll
        for (int c = 0; c < 4; ++c) {
            float4 w0 = *reinterpret_cast<const float4*>(wrow + 16 * c);
            float4 w1 = *reinterpret_cast<const float4*>(wrow + 16 * c + 4);
            float4 w2 = *reinterpret_cast<const float4*>(wrow + 16 * c + 8);
            float4 w3 = *reinterpret_cast<const float4*>(wrow + 16 * c + 12);
#pragma unroll
            for (int t = 0; t < TT; ++t)
                FMA16(acc[t], &xs[t][16 * c], w0, w1, w2, w3);
        }
#pragma unroll
        for (int t = 0; t < TT; ++t) qkvs[t][tid] = acc[t];

        const int o2 = 128 + (tid >> 1);
        const int t0 = (tid & 1) * 5;
        float acc2[5];
        const float bq2 = bqkv[o2];
#pragma unroll
        for (int tt = 0; tt < 5; ++tt) acc2[tt] = bq2;
        const float* wrow2 = wqkv + (size_t)o2 * DD;
#pragma unroll
        for (int c = 0; c < 4; ++c) {
            float4 w0 = *reinterpret_cast<const float4*>(wrow2 + 16 * c);
            float4 w1 = *reinterpret_cast<const float4*>(wrow2 + 16 * c + 4);
            float4 w2 = *reinterpret_cast<const float4*>(wrow2 + 16 * c + 8);
            float4 w3 = *reinterpret_cast<const float4*>(wrow2 + 16 * c + 12);
#pragma unroll
            for (int tt = 0; tt < 5; ++tt)
                FMA16(acc2[tt], &xs[t0 + tt][16 * c], w0, w1, w2, w3);
        }
#pragma unroll
        for (int tt = 0; tt < 5; ++tt) qkvs[t0 + tt][o2] = acc2[tt];
    }
    __syncthreads();

    // ---- attention ----
    if (tid < NHEAD * TT) {
        int h = tid / TT, t = tid % TT;
        float sc[TT];
        float mx = -1e30f;
#pragma unroll
        for (int s = 0; s < TT; ++s) {
            float a = 0.f;
#pragma unroll
            for (int d = 0; d < HDIM; ++d)
                a = fmaf(qkvs[t][h * HDIM + d], qkvs[s][DD + h * HDIM + d], a);
            a *= 0.25f;
            sc[s] = a;
            mx = fmaxf(mx, a);
        }
        float den = 0.f;
#pragma unroll
        for (int s = 0; s < TT; ++s) { sc[s] = fexp(sc[s] - mx); den += sc[s]; }
        float inv = frcp(den);
#pragma unroll
        for (int d = 0; d < HDIM; ++d) {
            float a = 0.f;
#pragma unroll
            for (int s = 0; s < TT; ++s)
                a = fmaf(sc[s], qkvs[s][2 * DD + h * HDIM + d], a);
            cs[t][h * HDIM + d] = a * inv;
        }
    }
    __syncthreads();

    // ---- out-proj + residual ----
    {
        const int o = tid & 63, t0 = (tid >> 6) * 5;
        float acc[5];
        const float bv = bo[o];
#pragma unroll
        for (int tt = 0; tt < 5; ++tt) acc[tt] = bv;
        const float* wrow = wo + (size_t)o * DD;
#pragma unroll
        for (int c = 0; c < 4; ++c) {
            float4 w0 = *reinterpret_cast<const float4*>(wrow + 16 * c);
            float4 w1 = *reinterpret_cast<const float4*>(wrow + 16 * c + 4);
            float4 w2 = *reinterpret_cast<const float4*>(wrow + 16 * c + 8);
            float4 w3 = *reinterpret_cast<const float4*>(wrow + 16 * c + 12);
#pragma unroll
            for (int tt = 0; tt < 5; ++tt)
                FMA16(acc[tt], &cs[t0 + tt][16 * c], w0, w1, w2, w3);
        }
#pragma unroll
        for (int tt = 0; tt < 5; ++tt)
            ys[t0 + tt][o] = xs[t0 + tt][o] + acc[tt];
    }
    __syncthreads();

    // ---- LN1 stats ----
    {
        const int t8 = tid >> 3, s8 = tid & 7;
        if (t8 < TT) {
            const float* yr = &ys[t8][s8 * 8];
            float s1 = 0.f;
#pragma unroll
            for (int c = 0; c < 8; c += 4) {
                float4 v = *reinterpret_cast<const float4*>(yr + c);
                s1 += (v.x + v.y) + (v.z + v.w);
            }
#pragma unroll
            for (int m = 1; m < 8; m <<= 1) s1 += __shfl_xor(s1, m);
            const float mean = s1 * (1.f / DD);
            float s2 = 0.f;
#pragma unroll
            for (int c = 0; c < 8; c += 4) {
                float4 v = *reinterpret_cast<const float4*>(yr + c);
                float d0 = v.x - mean, d1 = v.y - mean, d2 = v.z - mean, d3 = v.w - mean;
                s2 = fmaf(d0, d0, fmaf(d1, d1, fmaf(d2, d2, fmaf(d3, d3, s2))));
            }
#pragma unroll
            for (int m = 1; m < 8; m <<= 1) s2 += __shfl_xor(s2, m);
            if (s8 == 0) {
                mv[t8][0] = mean;
                mv[t8][1] = rsqrtf(s2 * (1.f / DD) + 1e-5f);
            }
        }
    }
    __syncthreads();
    for (int idx = tid; idx < TT * DD; idx += 128) {
        int t = idx / DD, o = idx % DD;
        xs[t][o] = (ys[t][o] - mv[t][0]) * mv[t][1] * g1[o] + b1[o];
    }
    __syncthreads();

    // ---- FF1 ----
    {
        const int pcol = tid & 63, t0 = (tid >> 6) * 5;
        float acc[5];
        const float bv = fb1[pcol];
#pragma unroll
        for (int tt = 0; tt < 5; ++tt) acc[tt] = bv;
        const float* wrow = fw1 + (size_t)pcol * DD;
#pragma unroll
        for (int c = 0; c < 4; ++c) {
            float4 w0 = *reinterpret_cast<const float4*>(wrow + 16 * c);
            float4 w1 = *reinterpret_cast<const float4*>(wrow + 16 * c + 4);
            float4 w2 = *reinterpret_cast<const float4*>(wrow + 16 * c + 8);
            float4 w3 = *reinterpret_cast<const float4*>(wrow + 16 * c + 12);
#pragma unroll
            for (int tt = 0; tt < 5; ++tt)
                FMA16(acc[tt], &xs[t0 + tt][16 * c], w0, w1, w2, w3);
        }
#pragma unroll
        for (int tt = 0; tt < 5; ++tt)
            cs[t0 + tt][pcol] = fmaxf(acc[tt], 0.f);
    }
    __syncthreads();

    // ---- FF2 + residual ----
    {
        const int o = tid & 63, t0 = (tid >> 6) * 5;
        float acc[5];
        const float bv = fb2[o];
#pragma unroll
        for (int tt = 0; tt < 5; ++tt) acc[tt] = bv;
        const float* wrow = fw2 + (size_t)o * DD;
#pragma unroll
        for (int c = 0; c < 4; ++c) {
            float4 w0 = *reinterpret_cast<const float4*>(wrow + 16 * c);
            float4 w1 = *reinterpret_cast<const float4*>(wrow + 16 * c + 4);
            float4 w2 = *reinterpret_cast<const float4*>(wrow + 16 * c + 8);
            float4 w3 = *reinterpret_cast<const float4*>(wrow + 16 * c + 12);
#pragma unroll
            for (int tt = 0; tt < 5; ++tt)
                FMA16(acc[tt], &cs[t0 + tt][16 * c], w0, w1, w2, w3);
        }
#pragma unroll
        for (int tt = 0; tt < 5; ++tt)
            ys[t0 + tt][o] = xs[t0 + tt][o] + acc[tt];
    }
    __syncthreads();

    // ---- LN2 stats ----
    {
        const int t8 = tid >> 3, s8 = tid & 7;
        if (t8 < TT) {
            const float* yr = &ys[t8][s8 * 8];
            float s1 = 0.f;
#pragma unroll
            for (int c = 0; c < 8; c += 4) {
                float4 v = *reinterpret_cast<const float4*>(yr + c);
                s1 += (v.x + v.y) + (v.z + v.w);
            }
#pragma unroll
            for (int m = 1; m < 8; m <<= 1) s1 += __shfl_xor(s1, m);
            const float mean = s1 * (1.f / DD);
            float s2 = 0.f;
#pragma unroll
            for (int c = 0; c < 8; c += 4) {
                float4 v = *reinterpret_cast<const float4*>(yr + c);
                float d0 = v.x - mean, d1 = v.y - mean, d2 = v.z - mean, d3 = v.w - mean;
                s2 = fmaf(d0, d0, fmaf(d1, d1, fmaf(d2, d2, fmaf(d3, d3, s2))));
            }
#pragma unroll
            for (int m = 1; m < 8; m <<= 1) s2 += __shfl_xor(s2, m);
            if (s8 == 0) {
                mv[t8][0] = mean;
                mv[t8][1] = rsqrtf(s2 * (1.f / DD) + 1e-5f);
            }
        }
    }
    __syncthreads();

    if (tid < DD) {
        float acc = 0.f;
#pragma unroll
        for (int t = 0; t < TT; ++t)
            acc += (ys[t][tid] - mv[t][0]) * mv[t][1];
        node_out[bid * DD + tid] = acc * g2[tid] * (1.f / TT) + b2[tid];
    }
}

// ---------------- GCN fused: 8 rows/block, 512 thr; wave = (4-row group, j-quarter) ----------------
// X-load shared across 4 rows in registers (4 fma/load); A rows on scalar path
__global__ __launch_bounds__(512) void k_gcn(
    const float* __restrict__ A, const float* __restrict__ X,
    const float* __restrict__ W, const float* __restrict__ b,
    float* __restrict__ Y)
{
    __shared__ __align__(16) float part[8][4][68];   // [local row][jq][channel]
    __shared__ __align__(16) float yrow[8][68];
    const int tid = threadIdx.x;
    const int lane = tid & 63;
    const int w = __builtin_amdgcn_readfirstlane(tid >> 6);   // 0..7
    const int rg = w >> 2, jq = w & 3;
    const int i0 = blockIdx.x * 8 + rg * 4;
    const int j0 = jq * (NN / 4);

    const float* a0 = A + (size_t)(i0 + 0) * NN + j0;   // wave-uniform -> scalar
    const float* a1 = A + (size_t)(i0 + 1) * NN + j0;
    const float* a2 = A + (size_t)(i0 + 2) * NN + j0;
    const float* a3 = A + (size_t)(i0 + 3) * NN + j0;
    const float* xp = X + (size_t)j0 * 64 + lane;

    float c0 = 0.f, c1 = 0.f, c2 = 0.f, c3 = 0.f;
#pragma unroll 8
    for (int jj = 0; jj < NN / 4; ++jj) {
        const float xv = xp[(size_t)jj * 64];
        c0 = fmaf(a0[jj], xv, c0);
        c1 = fmaf(a1[jj], xv, c1);
        c2 = fmaf(a2[jj], xv, c2);
        c3 = fmaf(a3[jj], xv, c3);
    }
    part[rg * 4 + 0][jq][lane] = c0;
    part[rg * 4 + 1][jq][lane] = c1;
    part[rg * 4 + 2][jq][lane] = c2;
    part[rg * 4 + 3][jq][lane] = c3;
    __syncthreads();

    // reduce quarters -> yrow
    {
        const int r2 = tid >> 6, o = tid & 63;
        yrow[r2][o] = (part[r2][0][o] + part[r2][1][o])
                    + (part[r2][2][o] + part[r2][3][o]);
    }
    __syncthreads();

    // W^T + bias + relu
    {
        const int r2 = tid >> 6, o = tid & 63;
        float z = b[o] + dot64(&yrow[r2][0], W + o * 64);
        Y[(size_t)(blockIdx.x * 8 + r2) * 64 + o] = fmaxf(z, 0.f);
    }
}

// ---------------- GCN layer 3 + fused edge-prep (gi, gjT4) ----------------
__global__ __launch_bounds__(512) void k_gcn3(
    const float* __restrict__ A, const float* __restrict__ X,
    const float* __restrict__ W, const float* __restrict__ b,
    const float* __restrict__ e_w1, const float* __restrict__ e_b1,
    float* __restrict__ gi_t, float* __restrict__ gjT4)
{
    __shared__ __align__(16) float part[8][4][68];
    __shared__ __align__(16) float yrow[8][68];
    __shared__ __align__(16) float nrow[8][68];
    const int tid = threadIdx.x;
    const int lane = tid & 63;
    const int w = __builtin_amdgcn_readfirstlane(tid >> 6);
    const int rg = w >> 2, jq = w & 3;
    const int i0 = blockIdx.x * 8 + rg * 4;
    const int j0 = jq * (NN / 4);

    const float* a0 = A + (size_t)(i0 + 0) * NN + j0;
    const float* a1 = A + (size_t)(i0 + 1) * NN + j0;
    const float* a2 = A + (size_t)(i0 + 2) * NN + j0;
    const float* a3 = A + (size_t)(i0 + 3) * NN + j0;
    const float* xp = X + (size_t)j0 * 64 + lane;

    float c0 = 0.f, c1 = 0.f, c2 = 0.f, c3 = 0.f;
#pragma unroll 8
    for (int jj = 0; jj < NN / 4; ++jj) {
        const float xv = xp[(size_t)jj * 64];
        c0 = fmaf(a0[jj], xv, c0);
        c1 = fmaf(a1[jj], xv, c1);
        c2 = fmaf(a2[jj], xv, c2);
        c3 = fmaf(a3[jj], xv, c3);
    }
    part[rg * 4 + 0][jq][lane] = c0;
    part[rg * 4 + 1][jq][lane] = c1;
    part[rg * 4 + 2][jq][lane] = c2;
    part[rg * 4 + 3][jq][lane] = c3;
    __syncthreads();

    {
        const int r2 = tid >> 6, o = tid & 63;
        yrow[r2][o] = (part[r2][0][o] + part[r2][1][o])
                    + (part[r2][2][o] + part[r2][3][o]);
    }
    __syncthreads();

    {
        const int r2 = tid >> 6, o = tid & 63;
        float z = b[o] + dot64(&yrow[r2][0], W + o * 64);
        nrow[r2][o] = fmaxf(z, 0.f);
    }
    __syncthreads();

    // gi + gjT4: 8 rows x 128 o = 1024 items, 2 per thread
#pragma unroll
    for (int pass = 0; pass < 2; ++pass) {
        const int idx = pass * 512 + tid;
        const int rr = idx >> 7, oo = idx & 127;
        const int i2 = blockIdx.x * 8 + rr;
        gi_t[(size_t)i2 * 128 + oo] = e_b1[oo] + dot64(&nrow[rr][0], e_w1 + oo * 138);
        gjT4[((size_t)(oo >> 2) * NN + i2) * 4 + (oo & 3)] =
            dot64(&nrow[rr][0], e_w1 + oo * 138 + 64);
    }
}

// ---------------- edge predictor: MFMA, 64 pairs/block, 4 waves, half-K tiles ----------------
__global__ __launch_bounds__(256, 8) void k_edge(
    const float* __restrict__ txyT,
    const float* __restrict__ gi_t,      // stride 128 per i
    const float* __restrict__ gjT4,
    const float* __restrict__ e_w1,
    const unsigned short* __restrict__ w2f,
    const float* __restrict__ e_b2,
    const float* __restrict__ e_w3, const float* __restrict__ e_b3,
    float* __restrict__ out)
{
    __shared__ __align__(16) unsigned short Ah[64 * 64];   // 8192 B
    __shared__ __align__(16) unsigned short Al[64 * 64];   // 8192 B
    __shared__ __align__(16) float hs[64][11];             // 2816 B (slot 10 = packed pi/pj)
    __shared__ __align__(16) float zsh[4][64];             // 1024 B

    const int tid  = threadIdx.x;
    const int lane = tid & 63;
    const int wv   = __builtin_amdgcn_readfirstlane(tid >> 6);  // wave 0..3
    const int p    = blockIdx.x * 64 + lane;

    // ---- wave 0: invert p, hist + dmin -> LDS (stores deferred) ----
    float dmin = 3.4e38f;
    if (wv == 0) {
        int pi0, pj0;
        invert_p(p, pi0, pj0);
#pragma unroll
        for (int t = 0; t < 10; ++t) {
            float dx = txyT[(size_t)(2 * t) * NN + pi0] - txyT[(size_t)(2 * t) * NN + pj0];
            float dy = txyT[(size_t)(2 * t + 1) * NN + pi0] - txyT[(size_t)(2 * t + 1) * NN + pj0];
            float d = fsqrt(fmaf(dx, dx, dy * dy));
            dmin = fminf(dmin, d);
            hs[lane][t] = fsigmoid_neg(50.f - 10.f * d);   // sigmoid(10d-50)
        }
        hs[lane][10] = __uint_as_float(((unsigned int)pi0 << 16) | (unsigned int)pj0);
    }
    __syncthreads();

    float hist[10];
#pragma unroll
    for (int t = 0; t < 10; ++t) hist[t] = hs[lane][t];
    const unsigned int pij = __float_as_uint(hs[lane][10]);
    const int pi = (int)(pij >> 16);
    const int pj = (int)(pij & 0xFFFFu);

    f32x4 acc[4];
#pragma unroll
    for (int pt = 0; pt < 4; ++pt) acc[pt] = (f32x4){0.f, 0.f, 0.f, 0.f};

#pragma unroll
    for (int h = 0; h < 2; ++h) {
        // ---- phase 1: 16 o's for o-window [h*64 + wv*16, +16) ----
        const int ob = h * 64 + wv * 16;
        const float* giRow = gi_t + (size_t)pi * 128 + ob;
        unsigned int ahp[8], alp[8];
#pragma unroll
        for (int q2 = 0; q2 < 4; ++q2) {
            const int o = ob + 4 * q2;
            const float4 gi4 = *reinterpret_cast<const float4*>(giRow + 4 * q2);
            const float4 gj4 = *reinterpret_cast<const float4*>(
                gjT4 + ((size_t)(o >> 2) * NN + pj) * 4);
            float av[4];
#pragma unroll
            for (int k = 0; k < 4; ++k) {
                float a = (&gi4.x)[k] + (&gj4.x)[k];
                const float* wh = e_w1 + (o + k) * 138 + 128;   // uniform -> scalar
#pragma unroll
                for (int t = 0; t < 10; ++t) a = fmaf(hist[t], wh[t], a);
                av[k] = fmaxf(a, 0.f);
            }
            const unsigned int u0 = __float_as_uint(av[0]), u1 = __float_as_uint(av[1]);
            const unsigned int u2 = __float_as_uint(av[2]), u3 = __float_as_uint(av[3]);
            ahp[2 * q2]     = __builtin_amdgcn_perm(u1, u0, 0x07060302);
            ahp[2 * q2 + 1] = __builtin_amdgcn_perm(u3, u2, 0x07060302);
            const float l0 = av[0] - __uint_as_float(u0 & 0xFFFF0000u);
            const float l1 = av[1] - __uint_as_float(u1 & 0xFFFF0000u);
            const float l2 = av[2] - __uint_as_float(u2 & 0xFFFF0000u);
            const float l3 = av[3] - __uint_as_float(u3 & 0xFFFF0000u);
            alp[2 * q2]     = __builtin_amdgcn_perm(__float_as_uint(l1), __float_as_uint(l0), 0x07060302);
            alp[2 * q2 + 1] = __builtin_amdgcn_perm(__float_as_uint(l3), __float_as_uint(l2), 0x07060302);
        }

        if (h == 1) __syncthreads();    // all waves done reading half-0 tiles

        // write tiles: row = lane (128 B rows), XOR row swizzle
        char* ahb = (char*)Ah + lane * 128;
        char* alb = (char*)Al + lane * 128;
#pragma unroll
        for (int c = 0; c < 2; ++c) {
            const int boff = ((wv << 5) + (c << 4)) ^ ((lane & 7) << 4);
            *reinterpret_cast<uint4*>(ahb + boff) = *reinterpret_cast<uint4*>(&ahp[4 * c]);
            *reinterpret_cast<uint4*>(alb + boff) = *reinterpret_cast<uint4*>(&alp[4 * c]);
        }

        // B-frags for this half: global kk = 2h + kkl
        bf16x8 bh[2], bl[2];
#pragma unroll
        for (int kkl = 0; kkl < 2; ++kkl) {
            const unsigned short* bb =
                w2f + ((size_t)(wv * 4 + 2 * h + kkl) * 2) * 512 + lane * 8;
            bh[kkl] = *reinterpret_cast<const bf16x8*>(bb);
            bl[kkl] = *reinterpret_cast<const bf16x8*>(bb + 512);
        }
        __syncthreads();

        // ---- MFMA: 2 kkl x 4 pt x 3 terms ----
        const char* ahr = (const char*)Ah;
        const char* alr = (const char*)Al;
#pragma unroll
        for (int kkl = 0; kkl < 2; ++kkl) {
#pragma unroll
            for (int pt = 0; pt < 4; ++pt) {
                const int row = pt * 16 + (lane & 15);
                const int boff = ((kkl << 6) + ((lane >> 4) << 4)) ^ ((row & 7) << 4);
                bf16x8 afh = *reinterpret_cast<const bf16x8*>(ahr + row * 128 + boff);
                bf16x8 afl = *reinterpret_cast<const bf16x8*>(alr + row * 128 + boff);
                acc[pt] = __builtin_amdgcn_mfma_f32_16x16x32_bf16(afh, bh[kkl], acc[pt], 0, 0, 0);
                acc[pt] = __builtin_amdgcn_mfma_f32_16x16x32_bf16(afh, bl[kkl], acc[pt], 0, 0, 0);
                acc[pt] = __builtin_amdgcn_mfma_f32_16x16x32_bf16(afl, bh[kkl], acc[pt], 0, 0, 0);
            }
        }
    }

    // ---- epilogue ----
    {
        const int m = wv * 16 + (lane & 15);
        const float w3v = e_w3[m];
        const float b2v = e_b2[m];
#pragma unroll
        for (int pt = 0; pt < 4; ++pt) {
            float zs0 = fmaxf(acc[pt][0] + b2v, 0.f) * w3v;
            float zs1 = fmaxf(acc[pt][1] + b2v, 0.f) * w3v;
            float zs2 = fmaxf(acc[pt][2] + b2v, 0.f) * w3v;
            float zs3 = fmaxf(acc[pt][3] + b2v, 0.f) * w3v;
#pragma unroll
            for (int msk = 1; msk < 16; msk <<= 1) {
                zs0 += __shfl_xor(zs0, msk);
                zs1 += __shfl_xor(zs1, msk);
                zs2 += __shfl_xor(zs2, msk);
                zs3 += __shfl_xor(zs3, msk);
            }
            if ((lane & 15) == 0) {
                const int pr = pt * 16 + (lane >> 4) * 4;
                zsh[wv][pr]     = zs0;
                zsh[wv][pr + 1] = zs1;
                zsh[wv][pr + 2] = zs2;
                zsh[wv][pr + 3] = zs3;
            }
        }
    }
    __syncthreads();

    // ---- deferred stores: prob + dmin + hist (hs still live) ----
    if (wv == 0) {
        float z = zsh[0][lane] + zsh[1][lane] + zsh[2][lane] + zsh[3][lane] + e_b3[0];
        out[p] = fsigmoid_neg(-z);
        out[PP + (size_t)p] = dmin;
        float* hp = out + 2 * (size_t)PP + (size_t)p * 10;
#pragma unroll
        for (int t = 0; t < 10; ++t) hp[t] = hs[lane][t];
    }
}

extern "C" void kernel_launch(void* const* d_in, const int* in_sizes, int n_in,
                              void* d_out, int out_size, void* d_ws, size_t ws_size,
                              hipStream_t stream) {
    const float* traj   = (const float*)d_in[0];
    const float* adj    = (const float*)d_in[1];
    const float* w_in   = (const float*)d_in[2];
    const float* b_in   = (const float*)d_in[3];
    const float* w_out  = (const float*)d_in[4];
    const float* b_out  = (const float*)d_in[5];
    const float* ln1g   = (const float*)d_in[6];
    const float* ln1b   = (const float*)d_in[7];
    const float* fw1    = (const float*)d_in[8];
    const float* fb1    = (const float*)d_in[9];
    const float* fw2    = (const float*)d_in[10];
    const float* fb2    = (const float*)d_in[11];
    const float* ln2g   = (const float*)d_in[12];
    const float* ln2b   = (const float*)d_in[13];
    const float* gcn_w  = (const float*)d_in[14];
    const float* gcn_b  = (const float*)d_in[15];
    const float* e_w1   = (const float*)d_in[16];
    const float* e_b1   = (const float*)d_in[17];
    const float* e_w2   = (const float*)d_in[18];
    const float* e_b2   = (const float*)d_in[19];
    const float* e_w3   = (const float*)d_in[20];
    const float* e_b3   = (const float*)d_in[21];

    float* ws    = (float*)d_ws;
    unsigned short* w2f = (unsigned short*)(ws + WS_W2F);
    float* txyT  = ws + WS_TXYT;
    float* gi    = ws + WS_GI;
    float* gjT4  = ws + WS_GJT4;
    float* nodeA = ws + WS_NODEA;
    float* nodeB = ws + WS_NODEB;

    k_transformer<<<NN + 84, 128, 0, stream>>>(traj, w_in, b_in, w_out, b_out,
                                               ln1g, ln1b, fw1, fb1, fw2, fb2,
                                               ln2g, ln2b, e_w2,
                                               nodeA, w2f, txyT);

    k_gcn <<<NN / 8, 512, 0, stream>>>(adj, nodeA, gcn_w,        gcn_b,       nodeB);
    k_gcn <<<NN / 8, 512, 0, stream>>>(adj, nodeB, gcn_w + 4096, gcn_b + 64,  nodeA);
    k_gcn3<<<NN / 8, 512, 0, stream>>>(adj, nodeA, gcn_w + 8192, gcn_b + 128,
                                       e_w1, e_b1, gi, gjT4);

    k_edge<<<PP / 64, 256, 0, stream>>>(txyT, gi, gjT4, e_w1, w2f, e_b2,
                                        e_w3, e_b3, (float*)d_out);
}

// Round 16
// 234.418 us; speedup vs baseline: 1.3636x; 1.0032x over previous
//
#include <hip/hip_runtime.h>
#include <hip/hip_bf16.h>
#include <math.h>

#define NN 1536
#define TT 10
#define DD 64
#define NHEAD 4
#define HDIM 16
#define PP 1178880   // NN*(NN-1)/2 = 4605 * 256 exactly; = 18420 * 64

// ws layout (float offsets)
#define WS_W2F   0        // 16384 ushort = 8192 float slots
#define WS_TXYT  8192     // 20*1536 = 30720 -> 38912
#define WS_GI    38912    // 1536*128 = 196608 -> 235520
#define WS_GJT4  235520   // 196608 -> 432128
#define WS_NODEA 432128   // 98304 -> 530432
#define WS_NODEB 530432   // 98304 -> 628736

using bf16x8 = __attribute__((ext_vector_type(8))) short;
using f32x4  = __attribute__((ext_vector_type(4))) float;

static __device__ __forceinline__ float fsqrt(float x) { return __builtin_amdgcn_sqrtf(x); }
static __device__ __forceinline__ float frcp(float x)  { return __builtin_amdgcn_rcpf(x); }
static __device__ __forceinline__ float fexp(float x)  {
    return __builtin_amdgcn_exp2f(x * 1.44269504088896f);
}
static __device__ __forceinline__ float fsigmoid_neg(float e_arg) {
    return frcp(1.f + fexp(e_arg));     // 1/(1+exp(e_arg))
}

static __device__ __forceinline__ unsigned short f2bf_rn(float f) {
    unsigned int u = __float_as_uint(f);
    unsigned int r = (u + 0x7FFFu + ((u >> 16) & 1u)) >> 16;
    return (unsigned short)r;
}
static __device__ __forceinline__ float bf2f(unsigned short h) {
    return __uint_as_float(((unsigned int)h) << 16);
}

static __device__ __forceinline__ float dot64(const float* __restrict__ a,
                                              const float* __restrict__ b) {
    float s = 0.f;
#pragma unroll
    for (int c = 0; c < 64; c += 4) {
        float4 av = *reinterpret_cast<const float4*>(a + c);
        float4 bv = *reinterpret_cast<const float4*>(b + c);
        s = fmaf(av.x, bv.x, s);
        s = fmaf(av.y, bv.y, s);
        s = fmaf(av.z, bv.z, s);
        s = fmaf(av.w, bv.w, s);
    }
    return s;
}

static __device__ __forceinline__ void invert_p(int p, int& io, int& jo) {
    const float Df = (float)((2 * NN - 1) * (2 * NN - 1) - 8 * p);
    int i = (int)(((float)(2 * NN - 1) - fsqrt(Df)) * 0.5f);
    i = i < 0 ? 0 : (i > NN - 2 ? NN - 2 : i);
    while (i * (2 * NN - 1 - i) / 2 > p) --i;
    while ((i + 1) * (2 * NN - 2 - i) / 2 <= p) ++i;
    io = i;
    jo = i + 1 + (p - i * (2 * NN - 1 - i) / 2);
}

// accumulate 16-wide chunk: acc += x[0..15] . w(4 float4 regs)
#define FMA16(acc, xr, w0, w1, w2, w3)                                   \
    {                                                                    \
        float4 x0 = *reinterpret_cast<const float4*>(xr);                \
        float4 x1 = *reinterpret_cast<const float4*>(xr + 4);            \
        float4 x2 = *reinterpret_cast<const float4*>(xr + 8);            \
        float4 x3 = *reinterpret_cast<const float4*>(xr + 12);           \
        acc = fmaf(x0.x, w0.x, acc); acc = fmaf(x0.y, w0.y, acc);        \
        acc = fmaf(x0.z, w0.z, acc); acc = fmaf(x0.w, w0.w, acc);        \
        acc = fmaf(x1.x, w1.x, acc); acc = fmaf(x1.y, w1.y, acc);        \
        acc = fmaf(x1.z, w1.z, acc); acc = fmaf(x1.w, w1.w, acc);        \
        acc = fmaf(x2.x, w2.x, acc); acc = fmaf(x2.y, w2.y, acc);        \
        acc = fmaf(x2.z, w2.z, acc); acc = fmaf(x2.w, w2.w, acc);        \
        acc = fmaf(x3.x, w3.x, acc); acc = fmaf(x3.y, w3.y, acc);        \
        acc = fmaf(x3.z, w3.z, acc); acc = fmaf(x3.w, w3.w, acc);        \
    }

// ---------------- Transformer encoder layer (+aux: w2f, txyT), 128 thr/block ----------------
__global__ __launch_bounds__(128) void k_transformer(
    const float* __restrict__ traj,
    const float* __restrict__ wqkv, const float* __restrict__ bqkv,
    const float* __restrict__ wo,   const float* __restrict__ bo,
    const float* __restrict__ g1,   const float* __restrict__ b1,
    const float* __restrict__ fw1,  const float* __restrict__ fb1,
    const float* __restrict__ fw2,  const float* __restrict__ fb2,
    const float* __restrict__ g2,   const float* __restrict__ b2,
    const float* __restrict__ e_w2,
    float* __restrict__ node_out, unsigned short* __restrict__ w2f,
    float* __restrict__ txyT)
{
    const int bid = blockIdx.x, tid = threadIdx.x;

    if (bid >= NN) {
        const int s = bid - NN;
        if (s < 64) {
#pragma unroll
            for (int q = 0; q < 2; ++q) {
                const int idx = s * 256 + q * 128 + tid;
                int e = idx & 7, lane = (idx >> 3) & 63;
                int half = (idx >> 9) & 1, kk = (idx >> 10) & 3, nt = (idx >> 12) & 3;
                int n = nt * 16 + (lane & 15);
                int k = kk * 32 + (lane >> 4) * 8 + e;
                float v = e_w2[n * 128 + k];
                unsigned short hi = f2bf_rn(v);
                unsigned short lo = f2bf_rn(v - bf2f(hi));
                w2f[idx] = half ? lo : hi;
            }
        } else {
            const int tc = s - 64;       // 0..19
            const int t = tc >> 1, c = tc & 1;
            for (int j = tid; j < NN; j += 128)
                txyT[(size_t)tc * NN + j] = traj[((size_t)j * TT + t) * DD + c];
        }
        return;
    }

    __shared__ __align__(16) float xs[TT][DD];
    __shared__ __align__(16) float qkvs[TT][3 * DD];
    __shared__ __align__(16) float cs[TT][DD];
    __shared__ __align__(16) float ys[TT][DD];
    __shared__ float mv[TT][2];

    const float* xg = traj + (size_t)bid * TT * DD;
    for (int idx = tid; idx < TT * DD; idx += 128)
        xs[idx / DD][idx % DD] = xg[idx];
    __syncthreads();

    // ---- QKV ----
    {
        float acc[TT];
        const float bq = bqkv[tid];
#pragma unroll
        for (int t = 0; t < TT; ++t) acc[t] = bq;
        const float* wrow = wqkv + (size_t)tid * DD;
#pragma unroll
        for (int c = 0; c < 4; ++c) {
            float4 w0 = *reinterpret_cast<const float4*>(wrow + 16 * c);
            float4 w1 = *reinterpret_cast<const float4*>(wrow + 16 * c + 4);
            float4 w2 = *reinterpret_cast<const float4*>(wrow + 16 * c + 8);
            float4 w3 = *reinterpret_cast<const float4*>(wrow + 16 * c + 12);
#pragma unroll
            for (int t = 0; t < TT; ++t)
                FMA16(acc[t], &xs[t][16 * c], w0, w1, w2, w3);
        }
#pragma unroll
        for (int t = 0; t < TT; ++t) qkvs[t][tid] = acc[t];

        const int o2 = 128 + (tid >> 1);
        const int t0 = (tid & 1) * 5;
        float acc2[5];
        const float bq2 = bqkv[o2];
#pragma unroll
        for (int tt = 0; tt < 5; ++tt) acc2[tt] = bq2;
        const float* wrow2 = wqkv + (size_t)o2 * DD;
#pragma unroll
        for (int c = 0; c < 4; ++c) {
            float4 w0 = *reinterpret_cast<const float4*>(wrow2 + 16 * c);
            float4 w1 = *reinterpret_cast<const float4*>(wrow2 + 16 * c + 4);
            float4 w2 = *reinterpret_cast<const float4*>(wrow2 + 16 * c + 8);
            float4 w3 = *reinterpret_cast<const float4*>(wrow2 + 16 * c + 12);
#pragma unroll
            for (int tt = 0; tt < 5; ++tt)
                FMA16(acc2[tt], &xs[t0 + tt][16 * c], w0, w1, w2, w3);
        }
#pragma unroll
        for (int tt = 0; tt < 5; ++tt) qkvs[t0 + tt][o2] = acc2[tt];
    }
    __syncthreads();

    // ---- attention ----
    if (tid < NHEAD * TT) {
        int h = tid / TT, t = tid % TT;
        float sc[TT];
        float mx = -1e30f;
#pragma unroll
        for (int s = 0; s < TT; ++s) {
            float a = 0.f;
#pragma unroll
            for (int d = 0; d < HDIM; ++d)
                a = fmaf(qkvs[t][h * HDIM + d], qkvs[s][DD + h * HDIM + d], a);
            a *= 0.25f;
            sc[s] = a;
            mx = fmaxf(mx, a);
        }
        float den = 0.f;
#pragma unroll
        for (int s = 0; s < TT; ++s) { sc[s] = fexp(sc[s] - mx); den += sc[s]; }
        float inv = frcp(den);
#pragma unroll
        for (int d = 0; d < HDIM; ++d) {
            float a = 0.f;
#pragma unroll
            for (int s = 0; s < TT; ++s)
                a = fmaf(sc[s], qkvs[s][2 * DD + h * HDIM + d], a);
            cs[t][h * HDIM + d] = a * inv;
        }
    }
    __syncthreads();

    // ---- out-proj + residual ----
    {
        const int o = tid & 63, t0 = (tid >> 6) * 5;
        float acc[5];
        const float bv = bo[o];
#pragma unroll
        for (int tt = 0; tt < 5; ++tt) acc[tt] = bv;
        const float* wrow = wo + (size_t)o * DD;
#pragma unroll
        for (int c = 0; c < 4; ++c) {
            float4 w0 = *reinterpret_cast<const float4*>(wrow + 16 * c);
            float4 w1 = *reinterpret_cast<const float4*>(wrow + 16 * c + 4);
            float4 w2 = *reinterpret_cast<const float4*>(wrow + 16 * c + 8);
            float4 w3 = *reinterpret_cast<const float4*>(wrow + 16 * c + 12);
#pragma unroll
            for (int tt = 0; tt < 5; ++tt)
                FMA16(acc[tt], &cs[t0 + tt][16 * c], w0, w1, w2, w3);
        }
#pragma unroll
        for (int tt = 0; tt < 5; ++tt)
            ys[t0 + tt][o] = xs[t0 + tt][o] + acc[tt];
    }
    __syncthreads();

    // ---- LN1 stats ----
    {
        const int t8 = tid >> 3, s8 = tid & 7;
        if (t8 < TT) {
            const float* yr = &ys[t8][s8 * 8];
            float s1 = 0.f;
#pragma unroll
            for (int c = 0; c < 8; c += 4) {
                float4 v = *reinterpret_cast<const float4*>(yr + c);
                s1 += (v.x + v.y) + (v.z + v.w);
            }
#pragma unroll
            for (int m = 1; m < 8; m <<= 1) s1 += __shfl_xor(s1, m);
            const float mean = s1 * (1.f / DD);
            float s2 = 0.f;
#pragma unroll
            for (int c = 0; c < 8; c += 4) {
                float4 v = *reinterpret_cast<const float4*>(yr + c);
                float d0 = v.x - mean, d1 = v.y - mean, d2 = v.z - mean, d3 = v.w - mean;
                s2 = fmaf(d0, d0, fmaf(d1, d1, fmaf(d2, d2, fmaf(d3, d3, s2))));
            }
#pragma unroll
            for (int m = 1; m < 8; m <<= 1) s2 += __shfl_xor(s2, m);
            if (s8 == 0) {
                mv[t8][0] = mean;
                mv[t8][1] = rsqrtf(s2 * (1.f / DD) + 1e-5f);
            }
        }
    }
    __syncthreads();
    for (int idx = tid; idx < TT * DD; idx += 128) {
        int t = idx / DD, o = idx % DD;
        xs[t][o] = (ys[t][o] - mv[t][0]) * mv[t][1] * g1[o] + b1[o];
    }
    __syncthreads();

    // ---- FF1 ----
    {
        const int pcol = tid & 63, t0 = (tid >> 6) * 5;
        float acc[5];
        const float bv = fb1[pcol];
#pragma unroll
        for (int tt = 0; tt < 5; ++tt) acc[tt] = bv;
        const float* wrow = fw1 + (size_t)pcol * DD;
#pragma unroll
        for (int c = 0; c < 4; ++c) {
            float4 w0 = *reinterpret_cast<const float4*>(wrow + 16 * c);
            float4 w1 = *reinterpret_cast<const float4*>(wrow + 16 * c + 4);
            float4 w2 = *reinterpret_cast<const float4*>(wrow + 16 * c + 8);
            float4 w3 = *reinterpret_cast<const float4*>(wrow + 16 * c + 12);
#pragma unroll
            for (int tt = 0; tt < 5; ++tt)
                FMA16(acc[tt], &xs[t0 + tt][16 * c], w0, w1, w2, w3);
        }
#pragma unroll
        for (int tt = 0; tt < 5; ++tt)
            cs[t0 + tt][pcol] = fmaxf(acc[tt], 0.f);
    }
    __syncthreads();

    // ---- FF2 + residual ----
    {
        const int o = tid & 63, t0 = (tid >> 6) * 5;
        float acc[5];
        const float bv = fb2[o];
#pragma unroll
        for (int tt = 0; tt < 5; ++tt) acc[tt] = bv;
        const float* wrow = fw2 + (size_t)o * DD;
#pragma unroll
        for (int c = 0; c < 4; ++c) {
            float4 w0 = *reinterpret_cast<const float4*>(wrow + 16 * c);
            float4 w1 = *reinterpret_cast<const float4*>(wrow + 16 * c + 4);
            float4 w2 = *reinterpret_cast<const float4*>(wrow + 16 * c + 8);
            float4 w3 = *reinterpret_cast<const float4*>(wrow + 16 * c + 12);
#pragma unroll
            for (int tt = 0; tt < 5; ++tt)
                FMA16(acc[tt], &cs[t0 + tt][16 * c], w0, w1, w2, w3);
        }
#pragma unroll
        for (int tt = 0; tt < 5; ++tt)
            ys[t0 + tt][o] = xs[t0 + tt][o] + acc[tt];
    }
    __syncthreads();

    // ---- LN2 stats ----
    {
        const int t8 = tid >> 3, s8 = tid & 7;
        if (t8 < TT) {
            const float* yr = &ys[t8][s8 * 8];
            float s1 = 0.f;
#pragma unroll
            for (int c = 0; c < 8; c += 4) {
                float4 v = *reinterpret_cast<const float4*>(yr + c);
                s1 += (v.x + v.y) + (v.z + v.w);
            }
#pragma unroll
            for (int m = 1; m < 8; m <<= 1) s1 += __shfl_xor(s1, m);
            const float mean = s1 * (1.f / DD);
            float s2 = 0.f;
#pragma unroll
            for (int c = 0; c < 8; c += 4) {
                float4 v = *reinterpret_cast<const float4*>(yr + c);
                float d0 = v.x - mean, d1 = v.y - mean, d2 = v.z - mean, d3 = v.w - mean;
                s2 = fmaf(d0, d0, fmaf(d1, d1, fmaf(d2, d2, fmaf(d3, d3, s2))));
            }
#pragma unroll
            for (int m = 1; m < 8; m <<= 1) s2 += __shfl_xor(s2, m);
            if (s8 == 0) {
                mv[t8][0] = mean;
                mv[t8][1] = rsqrtf(s2 * (1.f / DD) + 1e-5f);
            }
        }
    }
    __syncthreads();

    if (tid < DD) {
        float acc = 0.f;
#pragma unroll
        for (int t = 0; t < TT; ++t)
            acc += (ys[t][tid] - mv[t][0]) * mv[t][1];
        node_out[bid * DD + tid] = acc * g2[tid] * (1.f / TT) + b2[tid];
    }
}

// ---------------- GCN fused: 8 rows/block, 512 thr; wave = (4-row group, j-quarter) ----------------
__global__ __launch_bounds__(512) void k_gcn(
    const float* __restrict__ A, const float* __restrict__ X,
    const float* __restrict__ W, const float* __restrict__ b,
    float* __restrict__ Y)
{
    __shared__ __align__(16) float part[8][4][68];
    __shared__ __align__(16) float yrow[8][68];
    const int tid = threadIdx.x;
    const int lane = tid & 63;
    const int w = __builtin_amdgcn_readfirstlane(tid >> 6);   // 0..7
    const int rg = w >> 2, jq = w & 3;
    const int i0 = blockIdx.x * 8 + rg * 4;
    const int j0 = jq * (NN / 4);

    const float* a0 = A + (size_t)(i0 + 0) * NN + j0;   // wave-uniform -> scalar
    const float* a1 = A + (size_t)(i0 + 1) * NN + j0;
    const float* a2 = A + (size_t)(i0 + 2) * NN + j0;
    const float* a3 = A + (size_t)(i0 + 3) * NN + j0;
    const float* xp = X + (size_t)j0 * 64 + lane;

    float c0 = 0.f, c1 = 0.f, c2 = 0.f, c3 = 0.f;
#pragma unroll 8
    for (int jj = 0; jj < NN / 4; ++jj) {
        const float xv = xp[(size_t)jj * 64];
        c0 = fmaf(a0[jj], xv, c0);
        c1 = fmaf(a1[jj], xv, c1);
        c2 = fmaf(a2[jj], xv, c2);
        c3 = fmaf(a3[jj], xv, c3);
    }
    part[rg * 4 + 0][jq][lane] = c0;
    part[rg * 4 + 1][jq][lane] = c1;
    part[rg * 4 + 2][jq][lane] = c2;
    part[rg * 4 + 3][jq][lane] = c3;
    __syncthreads();

    {
        const int r2 = tid >> 6, o = tid & 63;
        yrow[r2][o] = (part[r2][0][o] + part[r2][1][o])
                    + (part[r2][2][o] + part[r2][3][o]);
    }
    __syncthreads();

    {
        const int r2 = tid >> 6, o = tid & 63;
        float z = b[o] + dot64(&yrow[r2][0], W + o * 64);
        Y[(size_t)(blockIdx.x * 8 + r2) * 64 + o] = fmaxf(z, 0.f);
    }
}

// ---------------- GCN layer 3 + fused edge-prep (gi, gjT4) ----------------
__global__ __launch_bounds__(512) void k_gcn3(
    const float* __restrict__ A, const float* __restrict__ X,
    const float* __restrict__ W, const float* __restrict__ b,
    const float* __restrict__ e_w1, const float* __restrict__ e_b1,
    float* __restrict__ gi_t, float* __restrict__ gjT4)
{
    __shared__ __align__(16) float part[8][4][68];
    __shared__ __align__(16) float yrow[8][68];
    __shared__ __align__(16) float nrow[8][68];
    const int tid = threadIdx.x;
    const int lane = tid & 63;
    const int w = __builtin_amdgcn_readfirstlane(tid >> 6);
    const int rg = w >> 2, jq = w & 3;
    const int i0 = blockIdx.x * 8 + rg * 4;
    const int j0 = jq * (NN / 4);

    const float* a0 = A + (size_t)(i0 + 0) * NN + j0;
    const float* a1 = A + (size_t)(i0 + 1) * NN + j0;
    const float* a2 = A + (size_t)(i0 + 2) * NN + j0;
    const float* a3 = A + (size_t)(i0 + 3) * NN + j0;
    const float* xp = X + (size_t)j0 * 64 + lane;

    float c0 = 0.f, c1 = 0.f, c2 = 0.f, c3 = 0.f;
#pragma unroll 8
    for (int jj = 0; jj < NN / 4; ++jj) {
        const float xv = xp[(size_t)jj * 64];
        c0 = fmaf(a0[jj], xv, c0);
        c1 = fmaf(a1[jj], xv, c1);
        c2 = fmaf(a2[jj], xv, c2);
        c3 = fmaf(a3[jj], xv, c3);
    }
    part[rg * 4 + 0][jq][lane] = c0;
    part[rg * 4 + 1][jq][lane] = c1;
    part[rg * 4 + 2][jq][lane] = c2;
    part[rg * 4 + 3][jq][lane] = c3;
    __syncthreads();

    {
        const int r2 = tid >> 6, o = tid & 63;
        yrow[r2][o] = (part[r2][0][o] + part[r2][1][o])
                    + (part[r2][2][o] + part[r2][3][o]);
    }
    __syncthreads();

    {
        const int r2 = tid >> 6, o = tid & 63;
        float z = b[o] + dot64(&yrow[r2][0], W + o * 64);
        nrow[r2][o] = fmaxf(z, 0.f);
    }
    __syncthreads();

#pragma unroll
    for (int pass = 0; pass < 2; ++pass) {
        const int idx = pass * 512 + tid;
        const int rr = idx >> 7, oo = idx & 127;
        const int i2 = blockIdx.x * 8 + rr;
        gi_t[(size_t)i2 * 128 + oo] = e_b1[oo] + dot64(&nrow[rr][0], e_w1 + oo * 138);
        gjT4[((size_t)(oo >> 2) * NN + i2) * 4 + (oo & 3)] =
            dot64(&nrow[rr][0], e_w1 + oo * 138 + 64);
    }
}

// ---------------- edge predictor: MFMA, 64 pairs/block, 4 waves, half-K tiles ----------------
// parallel hist (t-split across waves); coalesced hist store; 8 blocks/CU
__global__ __launch_bounds__(256, 8) void k_edge(
    const float* __restrict__ txyT,
    const float* __restrict__ gi_t,      // stride 128 per i
    const float* __restrict__ gjT4,
    const float* __restrict__ e_w1,
    const unsigned short* __restrict__ w2f,
    const float* __restrict__ e_b2,
    const float* __restrict__ e_w3, const float* __restrict__ e_b3,
    float* __restrict__ out)
{
    __shared__ __align__(16) unsigned short Ah[64 * 64];   // 8192 B
    __shared__ __align__(16) unsigned short Al[64 * 64];   // 8192 B
    __shared__ __align__(16) float hs[64][11];             // 2816 B
    __shared__ __align__(16) float zsh[4][64];             // 1024 B (dmin partials, then z)

    const int tid  = threadIdx.x;
    const int lane = tid & 63;
    const int wv   = __builtin_amdgcn_readfirstlane(tid >> 6);  // wave 0..3
    const int p    = blockIdx.x * 64 + lane;

    // every thread inverts its own pair (parallel, needed for phase 1 anyway)
    int pi, pj;
    invert_p(p, pi, pj);

    // ---- hist: t-split across waves; per-wave dmin partial -> zsh ----
    {
        float dminp = 3.4e38f;
        for (int t = wv; t < 10; t += 4) {
            float dx = txyT[(size_t)(2 * t) * NN + pi] - txyT[(size_t)(2 * t) * NN + pj];
            float dy = txyT[(size_t)(2 * t + 1) * NN + pi] - txyT[(size_t)(2 * t + 1) * NN + pj];
            float d = fsqrt(fmaf(dx, dx, dy * dy));
            dminp = fminf(dminp, d);
            hs[lane][t] = fsigmoid_neg(50.f - 10.f * d);   // sigmoid(10d-50)
        }
        zsh[wv][lane] = dminp;
    }
    __syncthreads();

    // wave 0 folds dmin into a register (zsh is reused by epilogue later)
    float dmin = 0.f;
    if (wv == 0)
        dmin = fminf(fminf(zsh[0][lane], zsh[1][lane]),
                     fminf(zsh[2][lane], zsh[3][lane]));

    float hist[10];
#pragma unroll
    for (int t = 0; t < 10; ++t) hist[t] = hs[lane][t];

    f32x4 acc[4];
#pragma unroll
    for (int pt = 0; pt < 4; ++pt) acc[pt] = (f32x4){0.f, 0.f, 0.f, 0.f};

#pragma unroll
    for (int h = 0; h < 2; ++h) {
        // ---- phase 1: 16 o's for o-window [h*64 + wv*16, +16) ----
        const int ob = h * 64 + wv * 16;
        const float* giRow = gi_t + (size_t)pi * 128 + ob;
        unsigned int ahp[8], alp[8];
#pragma unroll
        for (int q2 = 0; q2 < 4; ++q2) {
            const int o = ob + 4 * q2;
            const float4 gi4 = *reinterpret_cast<const float4*>(giRow + 4 * q2);
            const float4 gj4 = *reinterpret_cast<const float4*>(
                gjT4 + ((size_t)(o >> 2) * NN + pj) * 4);
            float av[4];
#pragma unroll
            for (int k = 0; k < 4; ++k) {
                float a = (&gi4.x)[k] + (&gj4.x)[k];
                const float* wh = e_w1 + (o + k) * 138 + 128;   // uniform -> scalar
#pragma unroll
                for (int t = 0; t < 10; ++t) a = fmaf(hist[t], wh[t], a);
                av[k] = fmaxf(a, 0.f);
            }
            const unsigned int u0 = __float_as_uint(av[0]), u1 = __float_as_uint(av[1]);
            const unsigned int u2 = __float_as_uint(av[2]), u3 = __float_as_uint(av[3]);
            ahp[2 * q2]     = __builtin_amdgcn_perm(u1, u0, 0x07060302);
            ahp[2 * q2 + 1] = __builtin_amdgcn_perm(u3, u2, 0x07060302);
            const float l0 = av[0] - __uint_as_float(u0 & 0xFFFF0000u);
            const float l1 = av[1] - __uint_as_float(u1 & 0xFFFF0000u);
            const float l2 = av[2] - __uint_as_float(u2 & 0xFFFF0000u);
            const float l3 = av[3] - __uint_as_float(u3 & 0xFFFF0000u);
            alp[2 * q2]     = __builtin_amdgcn_perm(__float_as_uint(l1), __float_as_uint(l0), 0x07060302);
            alp[2 * q2 + 1] = __builtin_amdgcn_perm(__float_as_uint(l3), __float_as_uint(l2), 0x07060302);
        }

        if (h == 1) __syncthreads();    // all waves done reading half-0 tiles

        // write tiles: row = lane (128 B rows), XOR row swizzle
        char* ahb = (char*)Ah + lane * 128;
        char* alb = (char*)Al + lane * 128;
#pragma unroll
        for (int c = 0; c < 2; ++c) {
            const int boff = ((wv << 5) + (c << 4)) ^ ((lane & 7) << 4);
            *reinterpret_cast<uint4*>(ahb + boff) = *reinterpret_cast<uint4*>(&ahp[4 * c]);
            *reinterpret_cast<uint4*>(alb + boff) = *reinterpret_cast<uint4*>(&alp[4 * c]);
        }

        // B-frags for this half: global kk = 2h + kkl
        bf16x8 bh[2], bl[2];
#pragma unroll
        for (int kkl = 0; kkl < 2; ++kkl) {
            const unsigned short* bb =
                w2f + ((size_t)(wv * 4 + 2 * h + kkl) * 2) * 512 + lane * 8;
            bh[kkl] = *reinterpret_cast<const bf16x8*>(bb);
            bl[kkl] = *reinterpret_cast<const bf16x8*>(bb + 512);
        }
        __syncthreads();

        // ---- MFMA: 2 kkl x 4 pt x 3 terms ----
        const char* ahr = (const char*)Ah;
        const char* alr = (const char*)Al;
#pragma unroll
        for (int kkl = 0; kkl < 2; ++kkl) {
#pragma unroll
            for (int pt = 0; pt < 4; ++pt) {
                const int row = pt * 16 + (lane & 15);
                const int boff = ((kkl << 6) + ((lane >> 4) << 4)) ^ ((row & 7) << 4);
                bf16x8 afh = *reinterpret_cast<const bf16x8*>(ahr + row * 128 + boff);
                bf16x8 afl = *reinterpret_cast<const bf16x8*>(alr + row * 128 + boff);
                acc[pt] = __builtin_amdgcn_mfma_f32_16x16x32_bf16(afh, bh[kkl], acc[pt], 0, 0, 0);
                acc[pt] = __builtin_amdgcn_mfma_f32_16x16x32_bf16(afh, bl[kkl], acc[pt], 0, 0, 0);
                acc[pt] = __builtin_amdgcn_mfma_f32_16x16x32_bf16(afl, bh[kkl], acc[pt], 0, 0, 0);
            }
        }
    }

    // ---- epilogue (overwrites zsh with z partials) ----
    {
        const int m = wv * 16 + (lane & 15);
        const float w3v = e_w3[m];
        const float b2v = e_b2[m];
#pragma unroll
        for (int pt = 0; pt < 4; ++pt) {
            float zs0 = fmaxf(acc[pt][0] + b2v, 0.f) * w3v;
            float zs1 = fmaxf(acc[pt][1] + b2v, 0.f) * w3v;
            float zs2 = fmaxf(acc[pt][2] + b2v, 0.f) * w3v;
            float zs3 = fmaxf(acc[pt][3] + b2v, 0.f) * w3v;
#pragma unroll
            for (int msk = 1; msk < 16; msk <<= 1) {
                zs0 += __shfl_xor(zs0, msk);
                zs1 += __shfl_xor(zs1, msk);
                zs2 += __shfl_xor(zs2, msk);
                zs3 += __shfl_xor(zs3, msk);
            }
            if ((lane & 15) == 0) {
                const int pr = pt * 16 + (lane >> 4) * 4;
                zsh[wv][pr]     = zs0;
                zsh[wv][pr + 1] = zs1;
                zsh[wv][pr + 2] = zs2;
                zsh[wv][pr + 3] = zs3;
            }
        }
    }
    __syncthreads();

    // ---- deferred stores: prob + dmin (wave0), hist coalesced (all threads) ----
    if (wv == 0) {
        float z = zsh[0][lane] + zsh[1][lane] + zsh[2][lane] + zsh[3][lane] + e_b3[0];
        out[p] = fsigmoid_neg(-z);
        out[PP + (size_t)p] = dmin;
    }
    {
        float* hb = out + 2 * (size_t)PP + (size_t)blockIdx.x * 640;
#pragma unroll
        for (int pass = 0; pass < 3; ++pass) {
            const int idx = pass * 256 + tid;
            if (idx < 640)
                hb[idx] = hs[idx / 10][idx % 10];
        }
    }
}

extern "C" void kernel_launch(void* const* d_in, const int* in_sizes, int n_in,
                              void* d_out, int out_size, void* d_ws, size_t ws_size,
                              hipStream_t stream) {
    const float* traj   = (const float*)d_in[0];
    const float* adj    = (const float*)d_in[1];
    const float* w_in   = (const float*)d_in[2];
    const float* b_in   = (const float*)d_in[3];
    const float* w_out  = (const float*)d_in[4];
    const float* b_out  = (const float*)d_in[5];
    const float* ln1g   = (const float*)d_in[6];
    const float* ln1b   = (const float*)d_in[7];
    const float* fw1    = (const float*)d_in[8];
    const float* fb1    = (const float*)d_in[9];
    const float* fw2    = (const float*)d_in[10];
    const float* fb2    = (const float*)d_in[11];
    const float* ln2g   = (const float*)d_in[12];
    const float* ln2b   = (const float*)d_in[13];
    const float* gcn_w  = (const float*)d_in[14];
    const float* gcn_b  = (const float*)d_in[15];
    const float* e_w1   = (const float*)d_in[16];
    const float* e_b1   = (const float*)d_in[17];
    const float* e_w2   = (const float*)d_in[18];
    const float* e_b2   = (const float*)d_in[19];
    const float* e_w3   = (const float*)d_in[20];
    const float* e_b3   = (const float*)d_in[21];

    float* ws    = (float*)d_ws;
    unsigned short* w2f = (unsigned short*)(ws + WS_W2F);
    float* txyT  = ws + WS_TXYT;
    float* gi    = ws + WS_GI;
    float* gjT4  = ws + WS_GJT4;
    float* nodeA = ws + WS_NODEA;
    float* nodeB = ws + WS_NODEB;

    k_transformer<<<NN + 84, 128, 0, stream>>>(traj, w_in, b_in, w_out, b_out,
                                               ln1g, ln1b, fw1, fb1, fw2, fb2,
                                               ln2g, ln2b, e_w2,
                                               nodeA, w2f, txyT);

    k_gcn <<<NN / 8, 512, 0, stream>>>(adj, nodeA, gcn_w,        gcn_b,       nodeB);
    k_gcn <<<NN / 8, 512, 0, stream>>>(adj, nodeB, gcn_w + 4096, gcn_b + 64,  nodeA);
    k_gcn3<<<NN / 8, 512, 0, stream>>>(adj, nodeA, gcn_w + 8192, gcn_b + 128,
                                       e_w1, e_b1, gi, gjT4);

    k_edge<<<PP / 64, 256, 0, stream>>>(txyT, gi, gjT4, e_w1, w2f, e_b2,
                                        e_w3, e_b3, (float*)d_out);
}

// Round 17
// 220.532 us; speedup vs baseline: 1.4495x; 1.0630x over previous
//
#include <hip/hip_runtime.h>
#include <hip/hip_bf16.h>
#include <math.h>

#define NN 1536
#define TT 10
#define DD 64
#define NHEAD 4
#define HDIM 16
#define PP 1178880   // NN*(NN-1)/2 = 4605 * 256 exactly; = 18420 * 64

// ws layout (float offsets)
#define WS_W2F   0        // 16384 ushort = 8192 float slots
#define WS_TXYT  8192     // 20*1536 = 30720 -> 38912
#define WS_GI    38912    // 1536*128 = 196608 -> 235520
#define WS_GJT4  235520   // 196608 -> 432128
#define WS_NODEA 432128   // 98304 -> 530432
#define WS_NODEB 530432   // 98304 -> 628736

using bf16x8 = __attribute__((ext_vector_type(8))) short;
using f32x4  = __attribute__((ext_vector_type(4))) float;

static __device__ __forceinline__ float fsqrt(float x) { return __builtin_amdgcn_sqrtf(x); }
static __device__ __forceinline__ float frcp(float x)  { return __builtin_amdgcn_rcpf(x); }
static __device__ __forceinline__ float fexp(float x)  {
    return __builtin_amdgcn_exp2f(x * 1.44269504088896f);
}
static __device__ __forceinline__ float fsigmoid_neg(float e_arg) {
    return frcp(1.f + fexp(e_arg));     // 1/(1+exp(e_arg))
}

static __device__ __forceinline__ unsigned short f2bf_rn(float f) {
    unsigned int u = __float_as_uint(f);
    unsigned int r = (u + 0x7FFFu + ((u >> 16) & 1u)) >> 16;
    return (unsigned short)r;
}
static __device__ __forceinline__ float bf2f(unsigned short h) {
    return __uint_as_float(((unsigned int)h) << 16);
}

static __device__ __forceinline__ float dot64(const float* __restrict__ a,
                                              const float* __restrict__ b) {
    float s = 0.f;
#pragma unroll
    for (int c = 0; c < 64; c += 4) {
        float4 av = *reinterpret_cast<const float4*>(a + c);
        float4 bv = *reinterpret_cast<const float4*>(b + c);
        s = fmaf(av.x, bv.x, s);
        s = fmaf(av.y, bv.y, s);
        s = fmaf(av.z, bv.z, s);
        s = fmaf(av.w, bv.w, s);
    }
    return s;
}

static __device__ __forceinline__ void invert_p(int p, int& io, int& jo) {
    const float Df = (float)((2 * NN - 1) * (2 * NN - 1) - 8 * p);
    int i = (int)(((float)(2 * NN - 1) - fsqrt(Df)) * 0.5f);
    i = i < 0 ? 0 : (i > NN - 2 ? NN - 2 : i);
    while (i * (2 * NN - 1 - i) / 2 > p) --i;
    while ((i + 1) * (2 * NN - 2 - i) / 2 <= p) ++i;
    io = i;
    jo = i + 1 + (p - i * (2 * NN - 1 - i) / 2);
}

// accumulate 16-wide chunk: acc += x[0..15] . w(4 float4 regs)
#define FMA16(acc, xr, w0, w1, w2, w3)                                   \
    {                                                                    \
        float4 x0 = *reinterpret_cast<const float4*>(xr);                \
        float4 x1 = *reinterpret_cast<const float4*>(xr + 4);            \
        float4 x2 = *reinterpret_cast<const float4*>(xr + 8);            \
        float4 x3 = *reinterpret_cast<const float4*>(xr + 12);           \
        acc = fmaf(x0.x, w0.x, acc); acc = fmaf(x0.y, w0.y, acc);        \
        acc = fmaf(x0.z, w0.z, acc); acc = fmaf(x0.w, w0.w, acc);        \
        acc = fmaf(x1.x, w1.x, acc); acc = fmaf(x1.y, w1.y, acc);        \
        acc = fmaf(x1.z, w1.z, acc); acc = fmaf(x1.w, w1.w, acc);        \
        acc = fmaf(x2.x, w2.x, acc); acc = fmaf(x2.y, w2.y, acc);        \
        acc = fmaf(x2.z, w2.z, acc); acc = fmaf(x2.w, w2.w, acc);        \
        acc = fmaf(x3.x, w3.x, acc); acc = fmaf(x3.y, w3.y, acc);        \
        acc = fmaf(x3.z, w3.z, acc); acc = fmaf(x3.w, w3.w, acc);        \
    }

// ---------------- Transformer encoder layer (+aux: w2f, txyT), 128 thr/block ----------------
__global__ __launch_bounds__(128) void k_transformer(
    const float* __restrict__ traj,
    const float* __restrict__ wqkv, const float* __restrict__ bqkv,
    const float* __restrict__ wo,   const float* __restrict__ bo,
    const float* __restrict__ g1,   const float* __restrict__ b1,
    const float* __restrict__ fw1,  const float* __restrict__ fb1,
    const float* __restrict__ fw2,  const float* __restrict__ fb2,
    const float* __restrict__ g2,   const float* __restrict__ b2,
    const float* __restrict__ e_w2,
    float* __restrict__ node_out, unsigned short* __restrict__ w2f,
    float* __restrict__ txyT)
{
    const int bid = blockIdx.x, tid = threadIdx.x;

    if (bid >= NN) {
        const int s = bid - NN;
        if (s < 64) {
#pragma unroll
            for (int q = 0; q < 2; ++q) {
                const int idx = s * 256 + q * 128 + tid;
                int e = idx & 7, lane = (idx >> 3) & 63;
                int half = (idx >> 9) & 1, kk = (idx >> 10) & 3, nt = (idx >> 12) & 3;
                int n = nt * 16 + (lane & 15);
                int k = kk * 32 + (lane >> 4) * 8 + e;
                float v = e_w2[n * 128 + k];
                unsigned short hi = f2bf_rn(v);
                unsigned short lo = f2bf_rn(v - bf2f(hi));
                w2f[idx] = half ? lo : hi;
            }
        } else {
            const int tc = s - 64;       // 0..19
            const int t = tc >> 1, c = tc & 1;
            for (int j = tid; j < NN; j += 128)
                txyT[(size_t)tc * NN + j] = traj[((size_t)j * TT + t) * DD + c];
        }
        return;
    }

    __shared__ __align__(16) float xs[TT][DD];
    __shared__ __align__(16) float qkvs[TT][3 * DD];
    __shared__ __align__(16) float cs[TT][DD];
    __shared__ __align__(16) float ys[TT][DD];
    __shared__ float mv[TT][2];

    const float* xg = traj + (size_t)bid * TT * DD;
    for (int idx = tid; idx < TT * DD; idx += 128)
        xs[idx / DD][idx % DD] = xg[idx];
    __syncthreads();

    // ---- QKV: part A reads x from GLOBAL (wave-uniform -> scalar path) ----
    {
        float acc[TT];
        const float bq = bqkv[tid];
#pragma unroll
        for (int t = 0; t < TT; ++t) acc[t] = bq;
        const float* wrow = wqkv + (size_t)tid * DD;
#pragma unroll
        for (int c = 0; c < 4; ++c) {
            float4 w0 = *reinterpret_cast<const float4*>(wrow + 16 * c);
            float4 w1 = *reinterpret_cast<const float4*>(wrow + 16 * c + 4);
            float4 w2 = *reinterpret_cast<const float4*>(wrow + 16 * c + 8);
            float4 w3 = *reinterpret_cast<const float4*>(wrow + 16 * c + 12);
#pragma unroll
            for (int t = 0; t < TT; ++t)
                FMA16(acc[t], xg + t * DD + 16 * c, w0, w1, w2, w3);
        }
#pragma unroll
        for (int t = 0; t < TT; ++t) qkvs[t][tid] = acc[t];

        const int o2 = 128 + (tid >> 1);
        const int t0 = (tid & 1) * 5;
        float acc2[5];
        const float bq2 = bqkv[o2];
#pragma unroll
        for (int tt = 0; tt < 5; ++tt) acc2[tt] = bq2;
        const float* wrow2 = wqkv + (size_t)o2 * DD;
#pragma unroll
        for (int c = 0; c < 4; ++c) {
            float4 w0 = *reinterpret_cast<const float4*>(wrow2 + 16 * c);
            float4 w1 = *reinterpret_cast<const float4*>(wrow2 + 16 * c + 4);
            float4 w2 = *reinterpret_cast<const float4*>(wrow2 + 16 * c + 8);
            float4 w3 = *reinterpret_cast<const float4*>(wrow2 + 16 * c + 12);
#pragma unroll
            for (int tt = 0; tt < 5; ++tt)
                FMA16(acc2[tt], &xs[t0 + tt][16 * c], w0, w1, w2, w3);
        }
#pragma unroll
        for (int tt = 0; tt < 5; ++tt) qkvs[t0 + tt][o2] = acc2[tt];
    }
    __syncthreads();

    // ---- attention ----
    if (tid < NHEAD * TT) {
        int h = tid / TT, t = tid % TT;
        float sc[TT];
        float mx = -1e30f;
#pragma unroll
        for (int s = 0; s < TT; ++s) {
            float a = 0.f;
#pragma unroll
            for (int d = 0; d < HDIM; ++d)
                a = fmaf(qkvs[t][h * HDIM + d], qkvs[s][DD + h * HDIM + d], a);
            a *= 0.25f;
            sc[s] = a;
            mx = fmaxf(mx, a);
        }
        float den = 0.f;
#pragma unroll
        for (int s = 0; s < TT; ++s) { sc[s] = fexp(sc[s] - mx); den += sc[s]; }
        float inv = frcp(den);
#pragma unroll
        for (int d = 0; d < HDIM; ++d) {
            float a = 0.f;
#pragma unroll
            for (int s = 0; s < TT; ++s)
                a = fmaf(sc[s], qkvs[s][2 * DD + h * HDIM + d], a);
            cs[t][h * HDIM + d] = a * inv;
        }
    }
    __syncthreads();

    // ---- out-proj + residual ----
    {
        const int o = tid & 63, t0 = (tid >> 6) * 5;
        float acc[5];
        const float bv = bo[o];
#pragma unroll
        for (int tt = 0; tt < 5; ++tt) acc[tt] = bv;
        const float* wrow = wo + (size_t)o * DD;
#pragma unroll
        for (int c = 0; c < 4; ++c) {
            float4 w0 = *reinterpret_cast<const float4*>(wrow + 16 * c);
            float4 w1 = *reinterpret_cast<const float4*>(wrow + 16 * c + 4);
            float4 w2 = *reinterpret_cast<const float4*>(wrow + 16 * c + 8);
            float4 w3 = *reinterpret_cast<const float4*>(wrow + 16 * c + 12);
#pragma unroll
            for (int tt = 0; tt < 5; ++tt)
                FMA16(acc[tt], &cs[t0 + tt][16 * c], w0, w1, w2, w3);
        }
#pragma unroll
        for (int tt = 0; tt < 5; ++tt)
            ys[t0 + tt][o] = xs[t0 + tt][o] + acc[tt];
    }
    __syncthreads();

    // ---- LN1 stats ----
    {
        const int t8 = tid >> 3, s8 = tid & 7;
        if (t8 < TT) {
            const float* yr = &ys[t8][s8 * 8];
            float s1 = 0.f;
#pragma unroll
            for (int c = 0; c < 8; c += 4) {
                float4 v = *reinterpret_cast<const float4*>(yr + c);
                s1 += (v.x + v.y) + (v.z + v.w);
            }
#pragma unroll
            for (int m = 1; m < 8; m <<= 1) s1 += __shfl_xor(s1, m);
            const float mean = s1 * (1.f / DD);
            float s2 = 0.f;
#pragma unroll
            for (int c = 0; c < 8; c += 4) {
                float4 v = *reinterpret_cast<const float4*>(yr + c);
                float d0 = v.x - mean, d1 = v.y - mean, d2 = v.z - mean, d3 = v.w - mean;
                s2 = fmaf(d0, d0, fmaf(d1, d1, fmaf(d2, d2, fmaf(d3, d3, s2))));
            }
#pragma unroll
            for (int m = 1; m < 8; m <<= 1) s2 += __shfl_xor(s2, m);
            if (s8 == 0) {
                mv[t8][0] = mean;
                mv[t8][1] = rsqrtf(s2 * (1.f / DD) + 1e-5f);
            }
        }
    }
    __syncthreads();
    for (int idx = tid; idx < TT * DD; idx += 128) {
        int t = idx / DD, o = idx % DD;
        xs[t][o] = (ys[t][o] - mv[t][0]) * mv[t][1] * g1[o] + b1[o];
    }
    __syncthreads();

    // ---- FF1 ----
    {
        const int pcol = tid & 63, t0 = (tid >> 6) * 5;
        float acc[5];
        const float bv = fb1[pcol];
#pragma unroll
        for (int tt = 0; tt < 5; ++tt) acc[tt] = bv;
        const float* wrow = fw1 + (size_t)pcol * DD;
#pragma unroll
        for (int c = 0; c < 4; ++c) {
            float4 w0 = *reinterpret_cast<const float4*>(wrow + 16 * c);
            float4 w1 = *reinterpret_cast<const float4*>(wrow + 16 * c + 4);
            float4 w2 = *reinterpret_cast<const float4*>(wrow + 16 * c + 8);
            float4 w3 = *reinterpret_cast<const float4*>(wrow + 16 * c + 12);
#pragma unroll
            for (int tt = 0; tt < 5; ++tt)
                FMA16(acc[tt], &xs[t0 + tt][16 * c], w0, w1, w2, w3);
        }
#pragma unroll
        for (int tt = 0; tt < 5; ++tt)
            cs[t0 + tt][pcol] = fmaxf(acc[tt], 0.f);
    }
    __syncthreads();

    // ---- FF2 + residual ----
    {
        const int o = tid & 63, t0 = (tid >> 6) * 5;
        float acc[5];
        const float bv = fb2[o];
#pragma unroll
        for (int tt = 0; tt < 5; ++tt) acc[tt] = bv;
        const float* wrow = fw2 + (size_t)o * DD;
#pragma unroll
        for (int c = 0; c < 4; ++c) {
            float4 w0 = *reinterpret_cast<const float4*>(wrow + 16 * c);
            float4 w1 = *reinterpret_cast<const float4*>(wrow + 16 * c + 4);
            float4 w2 = *reinterpret_cast<const float4*>(wrow + 16 * c + 8);
            float4 w3 = *reinterpret_cast<const float4*>(wrow + 16 * c + 12);
#pragma unroll
            for (int tt = 0; tt < 5; ++tt)
                FMA16(acc[tt], &cs[t0 + tt][16 * c], w0, w1, w2, w3);
        }
#pragma unroll
        for (int tt = 0; tt < 5; ++tt)
            ys[t0 + tt][o] = xs[t0 + tt][o] + acc[tt];
    }
    __syncthreads();

    // ---- LN2 stats ----
    {
        const int t8 = tid >> 3, s8 = tid & 7;
        if (t8 < TT) {
            const float* yr = &ys[t8][s8 * 8];
            float s1 = 0.f;
#pragma unroll
            for (int c = 0; c < 8; c += 4) {
                float4 v = *reinterpret_cast<const float4*>(yr + c);
                s1 += (v.x + v.y) + (v.z + v.w);
            }
#pragma unroll
            for (int m = 1; m < 8; m <<= 1) s1 += __shfl_xor(s1, m);
            const float mean = s1 * (1.f / DD);
            float s2 = 0.f;
#pragma unroll
            for (int c = 0; c < 8; c += 4) {
                float4 v = *reinterpret_cast<const float4*>(yr + c);
                float d0 = v.x - mean, d1 = v.y - mean, d2 = v.z - mean, d3 = v.w - mean;
                s2 = fmaf(d0, d0, fmaf(d1, d1, fmaf(d2, d2, fmaf(d3, d3, s2))));
            }
#pragma unroll
            for (int m = 1; m < 8; m <<= 1) s2 += __shfl_xor(s2, m);
            if (s8 == 0) {
                mv[t8][0] = mean;
                mv[t8][1] = rsqrtf(s2 * (1.f / DD) + 1e-5f);
            }
        }
    }
    __syncthreads();

    if (tid < DD) {
        float acc = 0.f;
#pragma unroll
        for (int t = 0; t < TT; ++t)
            acc += (ys[t][tid] - mv[t][0]) * mv[t][1];
        node_out[bid * DD + tid] = acc * g2[tid] * (1.f / TT) + b2[tid];
    }
}

// ---------------- GCN fused: 4 rows/block, 512 thr; wave = j-eighth, 4-row reg block ----------------
__global__ __launch_bounds__(512) void k_gcn(
    const float* __restrict__ A, const float* __restrict__ X,
    const float* __restrict__ W, const float* __restrict__ b,
    float* __restrict__ Y)
{
    __shared__ __align__(16) float part[4][8][68];
    __shared__ __align__(16) float yrow[4][68];
    const int tid = threadIdx.x;
    const int lane = tid & 63;
    const int w = __builtin_amdgcn_readfirstlane(tid >> 6);   // j-eighth 0..7
    const int i0 = blockIdx.x * 4;
    const int j0 = w * (NN / 8);

    const float* a0 = A + (size_t)(i0 + 0) * NN + j0;   // wave-uniform -> scalar
    const float* a1 = A + (size_t)(i0 + 1) * NN + j0;
    const float* a2 = A + (size_t)(i0 + 2) * NN + j0;
    const float* a3 = A + (size_t)(i0 + 3) * NN + j0;
    const float* xp = X + (size_t)j0 * 64 + lane;

    float c0 = 0.f, c1 = 0.f, c2 = 0.f, c3 = 0.f;
#pragma unroll 8
    for (int jj = 0; jj < NN / 8; ++jj) {
        const float xv = xp[(size_t)jj * 64];
        c0 = fmaf(a0[jj], xv, c0);
        c1 = fmaf(a1[jj], xv, c1);
        c2 = fmaf(a2[jj], xv, c2);
        c3 = fmaf(a3[jj], xv, c3);
    }
    part[0][w][lane] = c0;
    part[1][w][lane] = c1;
    part[2][w][lane] = c2;
    part[3][w][lane] = c3;
    __syncthreads();

    if (tid < 256) {
        const int r2 = tid >> 6, o = tid & 63;
        float s = 0.f;
#pragma unroll
        for (int k = 0; k < 8; ++k) s += part[r2][k][o];
        yrow[r2][o] = s;
    }
    __syncthreads();

    if (tid < 256) {
        const int r2 = tid >> 6, o = tid & 63;
        float z = b[o] + dot64(&yrow[r2][0], W + o * 64);
        Y[(size_t)(i0 + r2) * 64 + o] = fmaxf(z, 0.f);
    }
}

// ---------------- GCN layer 3 + fused edge-prep (gi, gjT4) ----------------
__global__ __launch_bounds__(512) void k_gcn3(
    const float* __restrict__ A, const float* __restrict__ X,
    const float* __restrict__ W, const float* __restrict__ b,
    const float* __restrict__ e_w1, const float* __restrict__ e_b1,
    float* __restrict__ gi_t, float* __restrict__ gjT4)
{
    __shared__ __align__(16) float part[4][8][68];
    __shared__ __align__(16) float yrow[4][68];
    __shared__ __align__(16) float nrow[4][68];
    const int tid = threadIdx.x;
    const int lane = tid & 63;
    const int w = __builtin_amdgcn_readfirstlane(tid >> 6);
    const int i0 = blockIdx.x * 4;
    const int j0 = w * (NN / 8);

    const float* a0 = A + (size_t)(i0 + 0) * NN + j0;
    const float* a1 = A + (size_t)(i0 + 1) * NN + j0;
    const float* a2 = A + (size_t)(i0 + 2) * NN + j0;
    const float* a3 = A + (size_t)(i0 + 3) * NN + j0;
    const float* xp = X + (size_t)j0 * 64 + lane;

    float c0 = 0.f, c1 = 0.f, c2 = 0.f, c3 = 0.f;
#pragma unroll 8
    for (int jj = 0; jj < NN / 8; ++jj) {
        const float xv = xp[(size_t)jj * 64];
        c0 = fmaf(a0[jj], xv, c0);
        c1 = fmaf(a1[jj], xv, c1);
        c2 = fmaf(a2[jj], xv, c2);
        c3 = fmaf(a3[jj], xv, c3);
    }
    part[0][w][lane] = c0;
    part[1][w][lane] = c1;
    part[2][w][lane] = c2;
    part[3][w][lane] = c3;
    __syncthreads();

    if (tid < 256) {
        const int r2 = tid >> 6, o = tid & 63;
        float s = 0.f;
#pragma unroll
        for (int k = 0; k < 8; ++k) s += part[r2][k][o];
        yrow[r2][o] = s;
    }
    __syncthreads();

    if (tid < 256) {
        const int r2 = tid >> 6, o = tid & 63;
        float z = b[o] + dot64(&yrow[r2][0], W + o * 64);
        nrow[r2][o] = fmaxf(z, 0.f);
    }
    __syncthreads();

    // gi + gjT4: 4 rows x 128 o = 512 items, one per thread
    {
        const int rr = tid >> 7;        // 0..3
        const int oo = tid & 127;
        const int i2 = i0 + rr;
        gi_t[(size_t)i2 * 128 + oo] = e_b1[oo] + dot64(&nrow[rr][0], e_w1 + oo * 138);
        gjT4[((size_t)(oo >> 2) * NN + i2) * 4 + (oo & 3)] =
            dot64(&nrow[rr][0], e_w1 + oo * 138 + 64);
    }
}

// ---------------- edge predictor: MFMA, 64 pairs/block, 4 waves, half-K tiles ----------------
// parallel hist (t-split across waves); coalesced hist store; 8 blocks/CU
__global__ __launch_bounds__(256, 8) void k_edge(
    const float* __restrict__ txyT,
    const float* __restrict__ gi_t,      // stride 128 per i
    const float* __restrict__ gjT4,
    const float* __restrict__ e_w1,
    const unsigned short* __restrict__ w2f,
    const float* __restrict__ e_b2,
    const float* __restrict__ e_w3, const float* __restrict__ e_b3,
    float* __restrict__ out)
{
    __shared__ __align__(16) unsigned short Ah[64 * 64];   // 8192 B
    __shared__ __align__(16) unsigned short Al[64 * 64];   // 8192 B
    __shared__ __align__(16) float hs[64][11];             // 2816 B
    __shared__ __align__(16) float zsh[4][64];             // 1024 B (dmin partials, then z)

    const int tid  = threadIdx.x;
    const int lane = tid & 63;
    const int wv   = __builtin_amdgcn_readfirstlane(tid >> 6);  // wave 0..3
    const int p    = blockIdx.x * 64 + lane;

    int pi, pj;
    invert_p(p, pi, pj);

    // ---- hist: t-split across waves; per-wave dmin partial -> zsh ----
    {
        float dminp = 3.4e38f;
        for (int t = wv; t < 10; t += 4) {
            float dx = txyT[(size_t)(2 * t) * NN + pi] - txyT[(size_t)(2 * t) * NN + pj];
            float dy = txyT[(size_t)(2 * t + 1) * NN + pi] - txyT[(size_t)(2 * t + 1) * NN + pj];
            float d = fsqrt(fmaf(dx, dx, dy * dy));
            dminp = fminf(dminp, d);
            hs[lane][t] = fsigmoid_neg(50.f - 10.f * d);   // sigmoid(10d-50)
        }
        zsh[wv][lane] = dminp;
    }
    __syncthreads();

    float dmin = 0.f;
    if (wv == 0)
        dmin = fminf(fminf(zsh[0][lane], zsh[1][lane]),
                     fminf(zsh[2][lane], zsh[3][lane]));

    float hist[10];
#pragma unroll
    for (int t = 0; t < 10; ++t) hist[t] = hs[lane][t];

    f32x4 acc[4];
#pragma unroll
    for (int pt = 0; pt < 4; ++pt) acc[pt] = (f32x4){0.f, 0.f, 0.f, 0.f};

#pragma unroll
    for (int h = 0; h < 2; ++h) {
        // ---- phase 1: 16 o's for o-window [h*64 + wv*16, +16) ----
        const int ob = h * 64 + wv * 16;
        const float* giRow = gi_t + (size_t)pi * 128 + ob;
        unsigned int ahp[8], alp[8];
#pragma unroll
        for (int q2 = 0; q2 < 4; ++q2) {
            const int o = ob + 4 * q2;
            const float4 gi4 = *reinterpret_cast<const float4*>(giRow + 4 * q2);
            const float4 gj4 = *reinterpret_cast<const float4*>(
                gjT4 + ((size_t)(o >> 2) * NN + pj) * 4);
            float av[4];
#pragma unroll
            for (int k = 0; k < 4; ++k) {
                float a = (&gi4.x)[k] + (&gj4.x)[k];
                const float* wh = e_w1 + (o + k) * 138 + 128;   // uniform -> scalar
#pragma unroll
                for (int t = 0; t < 10; ++t) a = fmaf(hist[t], wh[t], a);
                av[k] = fmaxf(a, 0.f);
            }
            const unsigned int u0 = __float_as_uint(av[0]), u1 = __float_as_uint(av[1]);
            const unsigned int u2 = __float_as_uint(av[2]), u3 = __float_as_uint(av[3]);
            ahp[2 * q2]     = __builtin_amdgcn_perm(u1, u0, 0x07060302);
            ahp[2 * q2 + 1] = __builtin_amdgcn_perm(u3, u2, 0x07060302);
            const float l0 = av[0] - __uint_as_float(u0 & 0xFFFF0000u);
            const float l1 = av[1] - __uint_as_float(u1 & 0xFFFF0000u);
            const float l2 = av[2] - __uint_as_float(u2 & 0xFFFF0000u);
            const float l3 = av[3] - __uint_as_float(u3 & 0xFFFF0000u);
            alp[2 * q2]     = __builtin_amdgcn_perm(__float_as_uint(l1), __float_as_uint(l0), 0x07060302);
            alp[2 * q2 + 1] = __builtin_amdgcn_perm(__float_as_uint(l3), __float_as_uint(l2), 0x07060302);
        }

        if (h == 1) __syncthreads();    // all waves done reading half-0 tiles

        // write tiles: row = lane (128 B rows), XOR row swizzle
        char* ahb = (char*)Ah + lane * 128;
        char* alb = (char*)Al + lane * 128;
#pragma unroll
        for (int c = 0; c < 2; ++c) {
            const int boff = ((wv << 5) + (c << 4)) ^ ((lane & 7) << 4);
            *reinterpret_cast<uint4*>(ahb + boff) = *reinterpret_cast<uint4*>(&ahp[4 * c]);
            *reinterpret_cast<uint4*>(alb + boff) = *reinterpret_cast<uint4*>(&alp[4 * c]);
        }

        // B-frags for this half: global kk = 2h + kkl
        bf16x8 bh[2], bl[2];
#pragma unroll
        for (int kkl = 0; kkl < 2; ++kkl) {
            const unsigned short* bb =
                w2f + ((size_t)(wv * 4 + 2 * h + kkl) * 2) * 512 + lane * 8;
            bh[kkl] = *reinterpret_cast<const bf16x8*>(bb);
            bl[kkl] = *reinterpret_cast<const bf16x8*>(bb + 512);
        }
        __syncthreads();

        // ---- MFMA: 2 kkl x 4 pt x 3 terms ----
        const char* ahr = (const char*)Ah;
        const char* alr = (const char*)Al;
#pragma unroll
        for (int kkl = 0; kkl < 2; ++kkl) {
#pragma unroll
            for (int pt = 0; pt < 4; ++pt) {
                const int row = pt * 16 + (lane & 15);
                const int boff = ((kkl << 6) + ((lane >> 4) << 4)) ^ ((row & 7) << 4);
                bf16x8 afh = *reinterpret_cast<const bf16x8*>(ahr + row * 128 + boff);
                bf16x8 afl = *reinterpret_cast<const bf16x8*>(alr + row * 128 + boff);
                acc[pt] = __builtin_amdgcn_mfma_f32_16x16x32_bf16(afh, bh[kkl], acc[pt], 0, 0, 0);
                acc[pt] = __builtin_amdgcn_mfma_f32_16x16x32_bf16(afh, bl[kkl], acc[pt], 0, 0, 0);
                acc[pt] = __builtin_amdgcn_mfma_f32_16x16x32_bf16(afl, bh[kkl], acc[pt], 0, 0, 0);
            }
        }
    }

    // ---- epilogue (overwrites zsh with z partials) ----
    {
        const int m = wv * 16 + (lane & 15);
        const float w3v = e_w3[m];
        const float b2v = e_b2[m];
#pragma unroll
        for (int pt = 0; pt < 4; ++pt) {
            float zs0 = fmaxf(acc[pt][0] + b2v, 0.f) * w3v;
            float zs1 = fmaxf(acc[pt][1] + b2v, 0.f) * w3v;
            float zs2 = fmaxf(acc[pt][2] + b2v, 0.f) * w3v;
            float zs3 = fmaxf(acc[pt][3] + b2v, 0.f) * w3v;
#pragma unroll
            for (int msk = 1; msk < 16; msk <<= 1) {
                zs0 += __shfl_xor(zs0, msk);
                zs1 += __shfl_xor(zs1, msk);
                zs2 += __shfl_xor(zs2, msk);
                zs3 += __shfl_xor(zs3, msk);
            }
            if ((lane & 15) == 0) {
                const int pr = pt * 16 + (lane >> 4) * 4;
                zsh[wv][pr]     = zs0;
                zsh[wv][pr + 1] = zs1;
                zsh[wv][pr + 2] = zs2;
                zsh[wv][pr + 3] = zs3;
            }
        }
    }
    __syncthreads();

    // ---- deferred stores: prob + dmin (wave0), hist coalesced (all threads) ----
    if (wv == 0) {
        float z = zsh[0][lane] + zsh[1][lane] + zsh[2][lane] + zsh[3][lane] + e_b3[0];
        out[p] = fsigmoid_neg(-z);
        out[PP + (size_t)p] = dmin;
    }
    {
        float* hb = out + 2 * (size_t)PP + (size_t)blockIdx.x * 640;
#pragma unroll
        for (int pass = 0; pass < 3; ++pass) {
            const int idx = pass * 256 + tid;
            if (idx < 640)
                hb[idx] = hs[idx / 10][idx % 10];
        }
    }
}

extern "C" void kernel_launch(void* const* d_in, const int* in_sizes, int n_in,
                              void* d_out, int out_size, void* d_ws, size_t ws_size,
                              hipStream_t stream) {
    const float* traj   = (const float*)d_in[0];
    const float* adj    = (const float*)d_in[1];
    const float* w_in   = (const float*)d_in[2];
    const float* b_in   = (const float*)d_in[3];
    const float* w_out  = (const float*)d_in[4];
    const float* b_out  = (const float*)d_in[5];
    const float* ln1g   = (const float*)d_in[6];
    const float* ln1b   = (const float*)d_in[7];
    const float* fw1    = (const float*)d_in[8];
    const float* fb1    = (const float*)d_in[9];
    const float* fw2    = (const float*)d_in[10];
    const float* fb2    = (const float*)d_in[11];
    const float* ln2g   = (const float*)d_in[12];
    const float* ln2b   = (const float*)d_in[13];
    const float* gcn_w  = (const float*)d_in[14];
    const float* gcn_b  = (const float*)d_in[15];
    const float* e_w1   = (const float*)d_in[16];
    const float* e_b1   = (const float*)d_in[17];
    const float* e_w2   = (const float*)d_in[18];
    const float* e_b2   = (const float*)d_in[19];
    const float* e_w3   = (const float*)d_in[20];
    const float* e_b3   = (const float*)d_in[21];

    float* ws    = (float*)d_ws;
    unsigned short* w2f = (unsigned short*)(ws + WS_W2F);
    float* txyT  = ws + WS_TXYT;
    float* gi    = ws + WS_GI;
    float* gjT4  = ws + WS_GJT4;
    float* nodeA = ws + WS_NODEA;
    float* nodeB = ws + WS_NODEB;

    k_transformer<<<NN + 84, 128, 0, stream>>>(traj, w_in, b_in, w_out, b_out,
                                               ln1g, ln1b, fw1, fb1, fw2, fb2,
                                               ln2g, ln2b, e_w2,
                                               nodeA, w2f, txyT);

    k_gcn <<<NN / 4, 512, 0, stream>>>(adj, nodeA, gcn_w,        gcn_b,       nodeB);
    k_gcn <<<NN / 4, 512, 0, stream>>>(adj, nodeB, gcn_w + 4096, gcn_b + 64,  nodeA);
    k_gcn3<<<NN / 4, 512, 0, stream>>>(adj, nodeA, gcn_w + 8192, gcn_b + 128,
                                       e_w1, e_b1, gi, gjT4);

    k_edge<<<PP / 64, 256, 0, stream>>>(txyT, gi, gjT4, e_w1, w2f, e_b2,
                                        e_w3, e_b3, (float*)d_out);
}